// Round 1
// baseline (1498.984 us; speedup 1.0000x reference)
//
#include <hip/hip_runtime.h>
#include <hip/hip_bf16.h>

#define N_NODES 100000
#define N_EDGES 3200000
#define KITER   10
#define ALPHA   0.1f
#define APAD    40   // padded LDS row (bf16 elems) for 32-k tiles

typedef __attribute__((ext_vector_type(4))) float f32x4;
typedef __attribute__((ext_vector_type(8))) short bf16x8;
typedef unsigned short u16;

__device__ inline float bf2f(u16 u) {
    unsigned int x = ((unsigned int)u) << 16;
    return __uint_as_float(x);
}
__device__ inline u16 f2bf(float f) {
    __hip_bfloat16 h = __float2bfloat16(f);
    return *reinterpret_cast<u16*>(&h);
}

// edge_index may arrive as int64 (reference dtype) or int32 (harness policy).
// Detect on device: int64 positive values < 2^31 have zero high dwords.
__global__ void k_detect(const unsigned int* e32, int* flag) {
    if (threadIdx.x == 0) {
        int is64 = 1;
        for (int i = 0; i < 64; ++i)
            if (e32[2 * i + 1] != 0u) { is64 = 0; break; }
        *flag = is64;
    }
}

__device__ inline int eidx(const void* p, int is64, int i) {
    if (is64) return (int)((const long long*)p)[i];
    return ((const int*)p)[i];
}

__global__ void k_count(const void* edges, const int* flag, int* deg) {
    int e = blockIdx.x * 256 + threadIdx.x;
    if (e >= N_EDGES) return;
    int is64 = *flag;
    int c = eidx(edges, is64, N_EDGES + e);  // col = target
    atomicAdd(&deg[c], 1);
}

__global__ void k_dinv(const int* deg, float* dinv) {
    int v = blockIdx.x * 256 + threadIdx.x;
    if (v >= N_NODES) return;
    dinv[v] = rsqrtf((float)(deg[v] + 1));   // +1 self loop; deg>=1 always
}

// single-block exclusive scan of deg -> ptr, cursor; ptr[N]=E
__global__ void k_scan(const int* deg, int* ptr, int* cursor) {
    __shared__ int lds[1024];
    const int CH = 98;  // 1024*98 = 100352 >= N_NODES
    int t = threadIdx.x;
    int base = t * CH;
    int s = 0;
    for (int i = 0; i < CH; ++i) {
        int idx = base + i;
        if (idx < N_NODES) s += deg[idx];
    }
    lds[t] = s;
    __syncthreads();
    for (int off = 1; off < 1024; off <<= 1) {
        int v = 0;
        if (t >= off) v = lds[t - off];
        __syncthreads();
        lds[t] += v;
        __syncthreads();
    }
    int run = lds[t] - s;  // exclusive prefix
    for (int i = 0; i < CH; ++i) {
        int idx = base + i;
        if (idx < N_NODES) {
            ptr[idx] = run;
            cursor[idx] = run;
            run += deg[idx];
        }
    }
    if (t == 1023) ptr[N_NODES] = lds[1023];
}

__global__ void k_fill(const void* edges, const int* flag, int* cursor, int* csr_src) {
    int e = blockIdx.x * 256 + threadIdx.x;
    if (e >= N_EDGES) return;
    int is64 = *flag;
    int r = eidx(edges, is64, e);            // row = source
    int c = eidx(edges, is64, N_EDGES + e);  // col = target
    int p = atomicAdd(&cursor[c], 1);
    csr_src[p] = r;
}

// W1 [500,256] f32 -> W1s bf16 swizzled [ks=16][n=256][kk=32], K zero-padded to 512
__global__ void k_wconv1(const float* W1, u16* W1s) {
    int idx = blockIdx.x * 256 + threadIdx.x;
    if (idx >= 16 * 256 * 32) return;
    int ks = idx / (256 * 32);
    int rem = idx % (256 * 32);
    int n = rem / 32, kk = rem % 32;
    int k = ks * 32 + kk;
    float v = (k < 500) ? W1[k * 256 + n] : 0.0f;
    W1s[idx] = f2bf(v);
}

// W2 [256,64] f32 -> W2s bf16 swizzled [ks=8][n=64][kk=32]
__global__ void k_wconv2(const float* W2, u16* W2s) {
    int idx = blockIdx.x * 256 + threadIdx.x;
    if (idx >= 8 * 64 * 32) return;
    int ks = idx / (64 * 32);
    int rem = idx % (64 * 32);
    int n = rem / 32, kk = rem % 32;
    int k = ks * 32 + kk;
    W2s[idx] = f2bf(W2[k * 64 + n]);
}

// Fused MLP: per block 64 rows. GEMM1 (K=500->512, N=256, bf16 MFMA) -> relu -> LDS
// -> GEMM2 (K=256, N=64) -> h_bf, zs0 = dinv*h
__global__ __launch_bounds__(256) void k_mlp(
    const float* __restrict__ x, const u16* __restrict__ W1s,
    const float* __restrict__ b1, const u16* __restrict__ W2s,
    const float* __restrict__ b2, const float* __restrict__ dinv,
    u16* __restrict__ h_bf, u16* __restrict__ zs0) {

    __shared__ u16 A_lds[64 * APAD];    // 5120 B
    __shared__ u16 B_lds[256 * APAD];   // 20480 B
    __shared__ u16 H_lds[64 * 264];     // 33792 B

    int t = threadIdx.x;
    int lane = t & 63, w = t >> 6;
    int m0 = blockIdx.x * 64;
    int cl = lane & 15, hi = lane >> 4;

    f32x4 acc[16];
    f32x4 zero = {0.f, 0.f, 0.f, 0.f};
#pragma unroll
    for (int i = 0; i < 16; ++i) acc[i] = zero;

    for (int ks = 0; ks < 16; ++ks) {
        // stage A: 64 rows x 32 k, f32 -> bf16
        {
            int r = t >> 2, k0 = (t & 3) * 8;
            int grow = m0 + r;
            int gk = ks * 32 + k0;
            u16 tmp[8];
            if (grow < N_NODES && gk + 8 <= 500) {
                const float4* p = (const float4*)(x + (size_t)grow * 500 + gk);
                float4 f0 = p[0], f1 = p[1];
                tmp[0] = f2bf(f0.x); tmp[1] = f2bf(f0.y);
                tmp[2] = f2bf(f0.z); tmp[3] = f2bf(f0.w);
                tmp[4] = f2bf(f1.x); tmp[5] = f2bf(f1.y);
                tmp[6] = f2bf(f1.z); tmp[7] = f2bf(f1.w);
            } else {
#pragma unroll
                for (int i = 0; i < 8; ++i) {
                    int k = gk + i;
                    float v = (grow < N_NODES && k < 500) ? x[(size_t)grow * 500 + k] : 0.0f;
                    tmp[i] = f2bf(v);
                }
            }
            uint4 u;
            u.x = (unsigned)tmp[0] | ((unsigned)tmp[1] << 16);
            u.y = (unsigned)tmp[2] | ((unsigned)tmp[3] << 16);
            u.z = (unsigned)tmp[4] | ((unsigned)tmp[5] << 16);
            u.w = (unsigned)tmp[6] | ((unsigned)tmp[7] << 16);
            *(uint4*)&A_lds[r * APAD + k0] = u;
        }
        // stage B: copy W1s panel (256 rows x 32 k) -> B_lds (row pad APAD)
        {
            const uint4* s4 = (const uint4*)(W1s + ks * 256 * 32 + t * 32);
            uint4 a0 = s4[0], a1 = s4[1], a2 = s4[2], a3 = s4[3];
            uint4* dst = (uint4*)&B_lds[t * APAD];
            dst[0] = a0; dst[1] = a1; dst[2] = a2; dst[3] = a3;
        }
        __syncthreads();
        bf16x8 a = *reinterpret_cast<const bf16x8*>(&A_lds[(w * 16 + cl) * APAD + 8 * hi]);
#pragma unroll
        for (int nt = 0; nt < 16; ++nt) {
            bf16x8 b = *reinterpret_cast<const bf16x8*>(&B_lds[(nt * 16 + cl) * APAD + 8 * hi]);
            acc[nt] = __builtin_amdgcn_mfma_f32_16x16x32_bf16(a, b, acc[nt], 0, 0, 0);
        }
        __syncthreads();
    }

    // epilogue 1: +b1, relu -> H_lds (bf16)
#pragma unroll
    for (int nt = 0; nt < 16; ++nt) {
        int col = nt * 16 + cl;
        float bb = b1[col];
#pragma unroll
        for (int r = 0; r < 4; ++r) {
            int row = w * 16 + hi * 4 + r;
            float v = acc[nt][r] + bb;
            v = fmaxf(v, 0.0f);
            H_lds[row * 264 + col] = f2bf(v);
        }
    }
    __syncthreads();

    // GEMM2: H_lds [64x256] @ W2 [256x64]
    f32x4 acc2[4];
#pragma unroll
    for (int i = 0; i < 4; ++i) acc2[i] = zero;
#pragma unroll
    for (int ks = 0; ks < 8; ++ks) {
        bf16x8 a = *reinterpret_cast<const bf16x8*>(&H_lds[(w * 16 + cl) * 264 + ks * 32 + 8 * hi]);
#pragma unroll
        for (int nt = 0; nt < 4; ++nt) {
            bf16x8 b = *reinterpret_cast<const bf16x8*>(W2s + (ks * 64 + nt * 16 + cl) * 32 + 8 * hi);
            acc2[nt] = __builtin_amdgcn_mfma_f32_16x16x32_bf16(a, b, acc2[nt], 0, 0, 0);
        }
    }
    // epilogue 2: +b2 -> h_bf, zs0 = dinv*h
#pragma unroll
    for (int nt = 0; nt < 4; ++nt) {
        int col = nt * 16 + cl;
        float bb = b2[col];
#pragma unroll
        for (int r = 0; r < 4; ++r) {
            int row = m0 + w * 16 + hi * 4 + r;
            if (row < N_NODES) {
                float v = acc2[nt][r] + bb;
                h_bf[(size_t)row * 64 + col] = f2bf(v);
                zs0[(size_t)row * 64 + col] = f2bf(dinv[row] * v);
            }
        }
    }
}

// One wave per node, lane = channel. zs = dinv .* z stored bf16.
// z_new[v] = 0.9*dinv[v]*(sum_src zs[src] + zs[v]) + 0.1*h[v]
__global__ __launch_bounds__(256) void k_prop(
    const u16* __restrict__ zs_in, const u16* __restrict__ h_bf,
    const float* __restrict__ dinv, const int* __restrict__ ptr,
    const int* __restrict__ csr_src, u16* __restrict__ zs_out,
    float* __restrict__ out, int last) {

    int lane = threadIdx.x & 63;
    int v = blockIdx.x * 4 + (threadIdx.x >> 6);
    if (v >= N_NODES) return;
    int s0 = ptr[v], s1 = ptr[v + 1];

    float a0 = 0.f, a1 = 0.f, a2 = 0.f, a3 = 0.f;
    for (int base = s0; base < s1; base += 64) {
        int e = base + lane;
        int sv = (e < s1) ? csr_src[e] : 0;
        int n = min(64, s1 - base);
        int j = 0;
        for (; j + 4 <= n; j += 4) {
            int u0 = __shfl(sv, j, 64);
            int u1 = __shfl(sv, j + 1, 64);
            int u2 = __shfl(sv, j + 2, 64);
            int u3 = __shfl(sv, j + 3, 64);
            a0 += bf2f(zs_in[(size_t)u0 * 64 + lane]);
            a1 += bf2f(zs_in[(size_t)u1 * 64 + lane]);
            a2 += bf2f(zs_in[(size_t)u2 * 64 + lane]);
            a3 += bf2f(zs_in[(size_t)u3 * 64 + lane]);
        }
        for (; j < n; ++j) {
            int u = __shfl(sv, j, 64);
            a0 += bf2f(zs_in[(size_t)u * 64 + lane]);
        }
    }
    float acc = bf2f(zs_in[(size_t)v * 64 + lane]) + ((a0 + a1) + (a2 + a3));
    float dv = dinv[v];
    float z = (1.0f - ALPHA) * dv * acc + ALPHA * bf2f(h_bf[(size_t)v * 64 + lane]);

    if (!last) {
        zs_out[(size_t)v * 64 + lane] = f2bf(dv * z);
    } else {
        float m = z;
#pragma unroll
        for (int off = 32; off >= 1; off >>= 1) m = fmaxf(m, __shfl_xor(m, off, 64));
        float p = expf(z - m);
        float s = p;
#pragma unroll
        for (int off = 32; off >= 1; off >>= 1) s += __shfl_xor(s, off, 64);
        out[(size_t)v * 64 + lane] = (z - m) - logf(s);
    }
}

extern "C" void kernel_launch(void* const* d_in, const int* in_sizes, int n_in,
                              void* d_out, int out_size, void* d_ws, size_t ws_size,
                              hipStream_t stream) {
    const float* x  = (const float*)d_in[0];
    const void* edges = d_in[1];
    const float* W1 = (const float*)d_in[2];
    const float* b1 = (const float*)d_in[3];
    const float* W2 = (const float*)d_in[4];
    const float* b2 = (const float*)d_in[5];
    float* out = (float*)d_out;

    char* ws = (char*)d_ws;
    size_t off = 0;
    auto alloc = [&](size_t bytes) -> void* {
        void* p = ws + off;
        off = (off + bytes + 255) & ~(size_t)255;
        return p;
    };
    int*   flag    = (int*)alloc(4);
    int*   deg     = (int*)alloc((size_t)N_NODES * 4);
    float* dinv    = (float*)alloc((size_t)N_NODES * 4);
    int*   ptr     = (int*)alloc((size_t)(N_NODES + 1) * 4);
    int*   cursor  = (int*)alloc((size_t)N_NODES * 4);
    int*   csr_src = (int*)alloc((size_t)N_EDGES * 4);
    u16*   W1s     = (u16*)alloc((size_t)16 * 256 * 32 * 2);
    u16*   W2s     = (u16*)alloc((size_t)8 * 64 * 32 * 2);
    u16*   h_bf    = (u16*)alloc((size_t)N_NODES * 64 * 2);
    u16*   zsA     = (u16*)alloc((size_t)N_NODES * 64 * 2);
    u16*   zsB     = (u16*)alloc((size_t)N_NODES * 64 * 2);

    hipMemsetAsync(deg, 0, (size_t)N_NODES * 4, stream);
    k_detect<<<1, 64, 0, stream>>>((const unsigned int*)edges, flag);
    k_count<<<(N_EDGES + 255) / 256, 256, 0, stream>>>(edges, flag, deg);
    k_dinv<<<(N_NODES + 255) / 256, 256, 0, stream>>>(deg, dinv);
    k_scan<<<1, 1024, 0, stream>>>(deg, ptr, cursor);
    k_fill<<<(N_EDGES + 255) / 256, 256, 0, stream>>>(edges, flag, cursor, csr_src);
    k_wconv1<<<(16 * 256 * 32 + 255) / 256, 256, 0, stream>>>(W1, W1s);
    k_wconv2<<<(8 * 64 * 32 + 255) / 256, 256, 0, stream>>>(W2, W2s);
    k_mlp<<<(N_NODES + 63) / 64, 256, 0, stream>>>(x, W1s, b1, W2s, b2, dinv, h_bf, zsA);

    const u16* zin = zsA;
    u16* zout = zsB;
    for (int k = 0; k < KITER; ++k) {
        int last = (k == KITER - 1) ? 1 : 0;
        k_prop<<<(N_NODES + 3) / 4, 256, 0, stream>>>(zin, h_bf, dinv, ptr, csr_src,
                                                      zout, out, last);
        const u16* t = zout;
        zout = (u16*)zin;
        zin = t;
    }
}

// Round 2
// 1299.370 us; speedup vs baseline: 1.1536x; 1.1536x over previous
//
#include <hip/hip_runtime.h>
#include <hip/hip_bf16.h>

#define N_NODES 100000
#define N_EDGES 3200000
#define KITER   10
#define ALPHA   0.1f
#define APAD    40   // padded LDS row (bf16 elems) for 32-k tiles

typedef __attribute__((ext_vector_type(4))) float f32x4;
typedef __attribute__((ext_vector_type(8))) short bf16x8;
typedef unsigned short u16;

__device__ inline float bf2f(u16 u) {
    unsigned int x = ((unsigned int)u) << 16;
    return __uint_as_float(x);
}
__device__ inline float bf2f_lo(unsigned int w) {  // low 16 bits as bf16
    return __uint_as_float(w << 16);
}
__device__ inline float bf2f_hi(unsigned int w) {  // high 16 bits as bf16
    return __uint_as_float(w & 0xffff0000u);
}
__device__ inline u16 f2bf(float f) {
    __hip_bfloat16 h = __float2bfloat16(f);
    return *reinterpret_cast<u16*>(&h);
}

// edge_index may arrive as int64 (reference dtype) or int32 (harness policy).
// Detect on device: int64 positive values < 2^31 have zero high dwords.
__global__ void k_detect(const unsigned int* e32, int* flag) {
    if (threadIdx.x == 0) {
        int is64 = 1;
        for (int i = 0; i < 64; ++i)
            if (e32[2 * i + 1] != 0u) { is64 = 0; break; }
        *flag = is64;
    }
}

__device__ inline int eidx(const void* p, int is64, int i) {
    if (is64) return (int)((const long long*)p)[i];
    return ((const int*)p)[i];
}

// convert edges to int32 row/col arrays AND count in-degrees (fused)
__global__ void k_convert_count(const void* edges, const int* flag,
                                int* row32, int* col32, int* deg) {
    int i = blockIdx.x * 256 + threadIdx.x;
    if (i >= N_EDGES) return;
    int is64 = *flag;
    int r = eidx(edges, is64, i);
    int c = eidx(edges, is64, N_EDGES + i);
    row32[i] = r;
    col32[i] = c;
    atomicAdd(&deg[c], 1);
}

// single-block exclusive scan of deg -> ptr, cursor; ptr[N]=E; fused dinv
__global__ void k_scan(const int* deg, int* ptr, int* cursor, float* dinv) {
    __shared__ int lds[1024];
    const int CH = 98;  // 1024*98 = 100352 >= N_NODES
    int t = threadIdx.x;
    int base = t * CH;
    int s = 0;
    for (int i = 0; i < CH; ++i) {
        int idx = base + i;
        if (idx < N_NODES) s += deg[idx];
    }
    lds[t] = s;
    __syncthreads();
    for (int off = 1; off < 1024; off <<= 1) {
        int v = 0;
        if (t >= off) v = lds[t - off];
        __syncthreads();
        lds[t] += v;
        __syncthreads();
    }
    int run = lds[t] - s;  // exclusive prefix
    for (int i = 0; i < CH; ++i) {
        int idx = base + i;
        if (idx < N_NODES) {
            int d = deg[idx];
            ptr[idx] = run;
            cursor[idx] = run;
            dinv[idx] = rsqrtf((float)(d + 1));  // +1 self loop
            run += d;
        }
    }
    if (t == 1023) ptr[N_NODES] = lds[1023];
}

// XCD-ownership fill: grp = blockIdx%8 owns target range [grp*12500, +12500).
// Every edge slice is scanned by all 8 groups; each csr line is written from
// exactly one XCD -> full-line coalescing in that XCD's L2 (kills the 15x
// write amplification of the naive scatter).
#define FILL_SLICES 128
__global__ __launch_bounds__(256) void k_fill2(const int* __restrict__ row32,
                                               const int* __restrict__ col32,
                                               int* cursor, int* __restrict__ csr_src) {
    int b = blockIdx.x;
    int grp = b & 7;
    int slice = b >> 3;
    int lo = grp * 12500, hi = lo + 12500;
    const int per = (N_EDGES + FILL_SLICES - 1) / FILL_SLICES;  // 25000
    int e0 = slice * per;
    int e1 = min(N_EDGES, e0 + per);
    for (int e = e0 + (int)threadIdx.x; e < e1; e += 256) {
        int c = col32[e];
        if (c >= lo && c < hi) {
            int r = row32[e];
            int p = atomicAdd(&cursor[c], 1);
            csr_src[p] = r;
        }
    }
}

// W1 [500,256] f32 -> W1s bf16 swizzled [ks=16][n=256][kk=32], K zero-padded to 512
__global__ void k_wconv1(const float* W1, u16* W1s) {
    int idx = blockIdx.x * 256 + threadIdx.x;
    if (idx >= 16 * 256 * 32) return;
    int ks = idx / (256 * 32);
    int rem = idx % (256 * 32);
    int n = rem / 32, kk = rem % 32;
    int k = ks * 32 + kk;
    float v = (k < 500) ? W1[k * 256 + n] : 0.0f;
    W1s[idx] = f2bf(v);
}

// W2 [256,64] f32 -> W2s bf16 swizzled [ks=8][n=64][kk=32]
__global__ void k_wconv2(const float* W2, u16* W2s) {
    int idx = blockIdx.x * 256 + threadIdx.x;
    if (idx >= 8 * 64 * 32) return;
    int ks = idx / (64 * 32);
    int rem = idx % (64 * 32);
    int n = rem / 32, kk = rem % 32;
    int k = ks * 32 + kk;
    W2s[idx] = f2bf(W2[k * 64 + n]);
}

// Fused MLP: per block 64 rows. GEMM1 (K=500->512, N=256, bf16 MFMA) -> relu -> LDS
// -> GEMM2 (K=256, N=64) -> h_bf, zs0 = dinv*h
__global__ __launch_bounds__(256) void k_mlp(
    const float* __restrict__ x, const u16* __restrict__ W1s,
    const float* __restrict__ b1, const u16* __restrict__ W2s,
    const float* __restrict__ b2, const float* __restrict__ dinv,
    u16* __restrict__ h_bf, u16* __restrict__ zs0) {

    __shared__ u16 A_lds[64 * APAD];
    __shared__ u16 B_lds[256 * APAD];
    __shared__ u16 H_lds[64 * 264];

    int t = threadIdx.x;
    int lane = t & 63, w = t >> 6;
    int m0 = blockIdx.x * 64;
    int cl = lane & 15, hi = lane >> 4;

    f32x4 acc[16];
    f32x4 zero = {0.f, 0.f, 0.f, 0.f};
#pragma unroll
    for (int i = 0; i < 16; ++i) acc[i] = zero;

    for (int ks = 0; ks < 16; ++ks) {
        {
            int r = t >> 2, k0 = (t & 3) * 8;
            int grow = m0 + r;
            int gk = ks * 32 + k0;
            u16 tmp[8];
            if (grow < N_NODES && gk + 8 <= 500) {
                const float4* p = (const float4*)(x + (size_t)grow * 500 + gk);
                float4 f0 = p[0], f1 = p[1];
                tmp[0] = f2bf(f0.x); tmp[1] = f2bf(f0.y);
                tmp[2] = f2bf(f0.z); tmp[3] = f2bf(f0.w);
                tmp[4] = f2bf(f1.x); tmp[5] = f2bf(f1.y);
                tmp[6] = f2bf(f1.z); tmp[7] = f2bf(f1.w);
            } else {
#pragma unroll
                for (int i = 0; i < 8; ++i) {
                    int k = gk + i;
                    float v = (grow < N_NODES && k < 500) ? x[(size_t)grow * 500 + k] : 0.0f;
                    tmp[i] = f2bf(v);
                }
            }
            uint4 u;
            u.x = (unsigned)tmp[0] | ((unsigned)tmp[1] << 16);
            u.y = (unsigned)tmp[2] | ((unsigned)tmp[3] << 16);
            u.z = (unsigned)tmp[4] | ((unsigned)tmp[5] << 16);
            u.w = (unsigned)tmp[6] | ((unsigned)tmp[7] << 16);
            *(uint4*)&A_lds[r * APAD + k0] = u;
        }
        {
            const uint4* s4 = (const uint4*)(W1s + ks * 256 * 32 + t * 32);
            uint4 a0 = s4[0], a1 = s4[1], a2 = s4[2], a3 = s4[3];
            uint4* dst = (uint4*)&B_lds[t * APAD];
            dst[0] = a0; dst[1] = a1; dst[2] = a2; dst[3] = a3;
        }
        __syncthreads();
        bf16x8 a = *reinterpret_cast<const bf16x8*>(&A_lds[(w * 16 + cl) * APAD + 8 * hi]);
#pragma unroll
        for (int nt = 0; nt < 16; ++nt) {
            bf16x8 b = *reinterpret_cast<const bf16x8*>(&B_lds[(nt * 16 + cl) * APAD + 8 * hi]);
            acc[nt] = __builtin_amdgcn_mfma_f32_16x16x32_bf16(a, b, acc[nt], 0, 0, 0);
        }
        __syncthreads();
    }

#pragma unroll
    for (int nt = 0; nt < 16; ++nt) {
        int col = nt * 16 + cl;
        float bb = b1[col];
#pragma unroll
        for (int r = 0; r < 4; ++r) {
            int row = w * 16 + hi * 4 + r;
            float v = acc[nt][r] + bb;
            v = fmaxf(v, 0.0f);
            H_lds[row * 264 + col] = f2bf(v);
        }
    }
    __syncthreads();

    f32x4 acc2[4];
#pragma unroll
    for (int i = 0; i < 4; ++i) acc2[i] = zero;
#pragma unroll
    for (int ks = 0; ks < 8; ++ks) {
        bf16x8 a = *reinterpret_cast<const bf16x8*>(&H_lds[(w * 16 + cl) * 264 + ks * 32 + 8 * hi]);
#pragma unroll
        for (int nt = 0; nt < 4; ++nt) {
            bf16x8 b = *reinterpret_cast<const bf16x8*>(W2s + (ks * 64 + nt * 16 + cl) * 32 + 8 * hi);
            acc2[nt] = __builtin_amdgcn_mfma_f32_16x16x32_bf16(a, b, acc2[nt], 0, 0, 0);
        }
    }
#pragma unroll
    for (int nt = 0; nt < 4; ++nt) {
        int col = nt * 16 + cl;
        float bb = b2[col];
#pragma unroll
        for (int r = 0; r < 4; ++r) {
            int row = m0 + w * 16 + hi * 4 + r;
            if (row < N_NODES) {
                float v = acc2[nt][r] + bb;
                h_bf[(size_t)row * 64 + col] = f2bf(v);
                zs0[(size_t)row * 64 + col] = f2bf(dinv[row] * v);
            }
        }
    }
}

// Propagation v2: one wave per node. Lane = (edge-slot g = lane>>4,
// channel-group c = lane&15, i.e. channels 4c..4c+3). Each 8B gather covers
// 4 edges per VMEM instruction; unroll x2 -> 1KB in flight per wave.
// z_new[v] = 0.9*dinv[v]*(sum_src zs[src] + zs[v]) + 0.1*h[v],  zs = dinv.*z
__global__ __launch_bounds__(256) void k_prop2(
    const u16* __restrict__ zs_in, const u16* __restrict__ h_bf,
    const float* __restrict__ dinv, const int* __restrict__ ptr,
    const int* __restrict__ csr_src, u16* __restrict__ zs_out,
    float* __restrict__ out, int last) {

    int lane = threadIdx.x & 63;
    int g = lane >> 4;   // edge slot 0..3
    int c = lane & 15;   // channels 4c..4c+3
    int v = blockIdx.x * 4 + (threadIdx.x >> 6);
    if (v >= N_NODES) return;
    int s0 = ptr[v], s1 = ptr[v + 1];

    float a0 = 0.f, a1 = 0.f, a2 = 0.f, a3 = 0.f;
    float e0 = 0.f, e1 = 0.f, e2 = 0.f, e3 = 0.f;
    for (int base = s0; base < s1; base += 64) {
        int nwin = min(64, s1 - base);
        int ei = base + lane;
        int sv = (ei < s1) ? csr_src[ei] : v;  // fallback: safe address
        int j = 0;
        for (; j + 8 <= nwin; j += 8) {
            int u0 = __shfl(sv, j + g, 64);
            int u1 = __shfl(sv, j + 4 + g, 64);
            uint2 q0 = *(const uint2*)(zs_in + (size_t)u0 * 64 + c * 4);
            uint2 q1 = *(const uint2*)(zs_in + (size_t)u1 * 64 + c * 4);
            a0 += bf2f_lo(q0.x); a1 += bf2f_hi(q0.x);
            a2 += bf2f_lo(q0.y); a3 += bf2f_hi(q0.y);
            e0 += bf2f_lo(q1.x); e1 += bf2f_hi(q1.x);
            e2 += bf2f_lo(q1.y); e3 += bf2f_hi(q1.y);
        }
        for (; j < nwin; j += 4) {
            int idx = j + g;
            int u = __shfl(sv, idx, 64);  // idx<=63 always; invalid lanes hold v
            uint2 q = *(const uint2*)(zs_in + (size_t)u * 64 + c * 4);
            if (idx < nwin) {
                a0 += bf2f_lo(q.x); a1 += bf2f_hi(q.x);
                a2 += bf2f_lo(q.y); a3 += bf2f_hi(q.y);
            }
        }
    }
    a0 += e0; a1 += e1; a2 += e2; a3 += e3;
    // reduce across the 4 edge slots
    a0 += __shfl_xor(a0, 16, 64); a0 += __shfl_xor(a0, 32, 64);
    a1 += __shfl_xor(a1, 16, 64); a1 += __shfl_xor(a1, 32, 64);
    a2 += __shfl_xor(a2, 16, 64); a2 += __shfl_xor(a2, 32, 64);
    a3 += __shfl_xor(a3, 16, 64); a3 += __shfl_xor(a3, 32, 64);

    float dv = dinv[v];
    uint2 qs = *(const uint2*)(zs_in + (size_t)v * 64 + c * 4);
    uint2 qh = *(const uint2*)(h_bf + (size_t)v * 64 + c * 4);
    float z0 = (1.0f - ALPHA) * dv * (a0 + bf2f_lo(qs.x)) + ALPHA * bf2f_lo(qh.x);
    float z1 = (1.0f - ALPHA) * dv * (a1 + bf2f_hi(qs.x)) + ALPHA * bf2f_hi(qh.x);
    float z2 = (1.0f - ALPHA) * dv * (a2 + bf2f_lo(qs.y)) + ALPHA * bf2f_lo(qh.y);
    float z3 = (1.0f - ALPHA) * dv * (a3 + bf2f_hi(qs.y)) + ALPHA * bf2f_hi(qh.y);

    if (!last) {
        if (g == 0) {
            uint2 o;
            o.x = (unsigned)f2bf(dv * z0) | ((unsigned)f2bf(dv * z1) << 16);
            o.y = (unsigned)f2bf(dv * z2) | ((unsigned)f2bf(dv * z3) << 16);
            *(uint2*)(zs_out + (size_t)v * 64 + c * 4) = o;
        }
    } else {
        float m = fmaxf(fmaxf(z0, z1), fmaxf(z2, z3));
#pragma unroll
        for (int off = 1; off <= 8; off <<= 1) m = fmaxf(m, __shfl_xor(m, off, 64));
        float p = expf(z0 - m) + expf(z1 - m) + expf(z2 - m) + expf(z3 - m);
#pragma unroll
        for (int off = 1; off <= 8; off <<= 1) p += __shfl_xor(p, off, 64);
        float ls = logf(p);
        if (g == 0) {
            float4 o = {z0 - m - ls, z1 - m - ls, z2 - m - ls, z3 - m - ls};
            *(float4*)(out + (size_t)v * 64 + c * 4) = o;
        }
    }
}

extern "C" void kernel_launch(void* const* d_in, const int* in_sizes, int n_in,
                              void* d_out, int out_size, void* d_ws, size_t ws_size,
                              hipStream_t stream) {
    const float* x  = (const float*)d_in[0];
    const void* edges = d_in[1];
    const float* W1 = (const float*)d_in[2];
    const float* b1 = (const float*)d_in[3];
    const float* W2 = (const float*)d_in[4];
    const float* b2 = (const float*)d_in[5];
    float* out = (float*)d_out;

    char* ws = (char*)d_ws;
    size_t off = 0;
    auto alloc = [&](size_t bytes) -> void* {
        void* p = ws + off;
        off = (off + bytes + 255) & ~(size_t)255;
        return p;
    };
    int*   flag    = (int*)alloc(4);
    int*   deg     = (int*)alloc((size_t)N_NODES * 4);
    float* dinv    = (float*)alloc((size_t)N_NODES * 4);
    int*   ptr     = (int*)alloc((size_t)(N_NODES + 1) * 4);
    int*   cursor  = (int*)alloc((size_t)N_NODES * 4);
    int*   csr_src = (int*)alloc((size_t)N_EDGES * 4);
    u16*   W1s     = (u16*)alloc((size_t)16 * 256 * 32 * 2);
    u16*   W2s     = (u16*)alloc((size_t)8 * 64 * 32 * 2);
    u16*   h_bf    = (u16*)alloc((size_t)N_NODES * 64 * 2);
    u16*   zsA     = (u16*)alloc((size_t)N_NODES * 64 * 2);
    int*   row32   = (int*)alloc((size_t)N_EDGES * 4);  // aliased as zsB after fill
    int*   col32   = (int*)alloc((size_t)N_EDGES * 4);
    u16*   zsB     = (u16*)row32;  // row32 dead after k_fill2; N_EDGES*4 == N*64*2

    hipMemsetAsync(deg, 0, (size_t)N_NODES * 4, stream);
    k_detect<<<1, 64, 0, stream>>>((const unsigned int*)edges, flag);
    k_convert_count<<<(N_EDGES + 255) / 256, 256, 0, stream>>>(edges, flag, row32, col32, deg);
    k_scan<<<1, 1024, 0, stream>>>(deg, ptr, cursor, dinv);
    k_fill2<<<8 * FILL_SLICES, 256, 0, stream>>>(row32, col32, cursor, csr_src);
    k_wconv1<<<(16 * 256 * 32 + 255) / 256, 256, 0, stream>>>(W1, W1s);
    k_wconv2<<<(8 * 64 * 32 + 255) / 256, 256, 0, stream>>>(W2, W2s);
    k_mlp<<<(N_NODES + 63) / 64, 256, 0, stream>>>(x, W1s, b1, W2s, b2, dinv, h_bf, zsA);

    const u16* zin = zsA;
    u16* zout = zsB;
    for (int k = 0; k < KITER; ++k) {
        int last = (k == KITER - 1) ? 1 : 0;
        k_prop2<<<(N_NODES + 3) / 4, 256, 0, stream>>>(zin, h_bf, dinv, ptr, csr_src,
                                                       zout, out, last);
        u16* t = zout;
        zout = (u16*)zin;
        zin = t;
    }
}

// Round 3
// 959.798 us; speedup vs baseline: 1.5618x; 1.3538x over previous
//
#include <hip/hip_runtime.h>
#include <hip/hip_bf16.h>

#define N_NODES 100000
#define N_EDGES 3200000
#define KITER   10
#define ALPHA   0.1f
#define APAD    40   // padded LDS row (bf16 elems) for 32-k tiles

#define SCAN_BS 512
#define SCAN_NB ((N_NODES + SCAN_BS - 1) / SCAN_BS)   // 196

typedef __attribute__((ext_vector_type(4))) float f32x4;
typedef __attribute__((ext_vector_type(8))) short bf16x8;
typedef unsigned short u16;

__device__ inline float bf2f(u16 u) {
    unsigned int x = ((unsigned int)u) << 16;
    return __uint_as_float(x);
}
__device__ inline float bf2f_lo(unsigned int w) { return __uint_as_float(w << 16); }
__device__ inline float bf2f_hi(unsigned int w) { return __uint_as_float(w & 0xffff0000u); }
__device__ inline u16 f2bf(float f) {
    __hip_bfloat16 h = __float2bfloat16(f);
    return *reinterpret_cast<u16*>(&h);
}

// edge_index may arrive as int64 (reference dtype) or int32 (harness policy).
__global__ void k_detect(const unsigned int* e32, int* flag) {
    if (threadIdx.x == 0) {
        int is64 = 1;
        for (int i = 0; i < 64; ++i)
            if (e32[2 * i + 1] != 0u) { is64 = 0; break; }
        *flag = is64;
    }
}

__device__ inline int eidx(const void* p, int is64, int i) {
    if (is64) return (int)((const long long*)p)[i];
    return ((const int*)p)[i];
}

// convert edges to int32 row/col arrays AND count in-degrees (fused)
__global__ void k_convert_count(const void* edges, const int* flag,
                                int* row32, int* col32, int* deg) {
    int i = blockIdx.x * 256 + threadIdx.x;
    if (i >= N_EDGES) return;
    int is64 = *flag;
    int r = eidx(edges, is64, i);
    int c = eidx(edges, is64, N_EDGES + i);
    row32[i] = r;
    col32[i] = c;
    atomicAdd(&deg[c], 1);
}

// ---- two-level scan: local scan -> scan of block sums -> apply ----
__global__ __launch_bounds__(SCAN_BS) void k_scan_part(const int* __restrict__ deg,
                                                       int* __restrict__ ptr,
                                                       int* __restrict__ bsum) {
    __shared__ int lds[SCAN_BS];
    int t = threadIdx.x;
    int idx = blockIdx.x * SCAN_BS + t;
    int s = (idx < N_NODES) ? deg[idx] : 0;
    lds[t] = s;
    __syncthreads();
#pragma unroll
    for (int off = 1; off < SCAN_BS; off <<= 1) {
        int v = (t >= off) ? lds[t - off] : 0;
        __syncthreads();
        lds[t] += v;
        __syncthreads();
    }
    if (idx < N_NODES) ptr[idx] = lds[t] - s;     // exclusive local
    if (t == SCAN_BS - 1) bsum[blockIdx.x] = lds[t];
}

__global__ __launch_bounds__(256) void k_scan_bsum(const int* __restrict__ bsum,
                                                   int* __restrict__ boff,
                                                   int* __restrict__ ptr) {
    __shared__ int lds[256];
    int t = threadIdx.x;
    int s = (t < SCAN_NB) ? bsum[t] : 0;
    lds[t] = s;
    __syncthreads();
#pragma unroll
    for (int off = 1; off < 256; off <<= 1) {
        int v = (t >= off) ? lds[t - off] : 0;
        __syncthreads();
        lds[t] += v;
        __syncthreads();
    }
    if (t < SCAN_NB) boff[t] = lds[t] - s;        // exclusive
    if (t == 255) ptr[N_NODES] = lds[t];          // total (== N_EDGES)
}

__global__ __launch_bounds__(SCAN_BS) void k_scan_apply(const int* __restrict__ deg,
                                                        const int* __restrict__ boff,
                                                        int* __restrict__ ptr,
                                                        int* __restrict__ cursor,
                                                        float* __restrict__ dinv) {
    int idx = blockIdx.x * SCAN_BS + threadIdx.x;
    if (idx >= N_NODES) return;
    int p = ptr[idx] + boff[blockIdx.x];
    ptr[idx] = p;
    cursor[idx] = p;
    dinv[idx] = rsqrtf((float)(deg[idx] + 1));    // +1 self loop
}

// XCD-ownership fill: grp = blockIdx%8 owns target range [grp*12500, +12500).
#define FILL_SLICES 128
__global__ __launch_bounds__(256) void k_fill2(const int* __restrict__ row32,
                                               const int* __restrict__ col32,
                                               int* cursor, int* __restrict__ csr_src) {
    int b = blockIdx.x;
    int grp = b & 7;
    int slice = b >> 3;
    int lo = grp * 12500, hi = lo + 12500;
    const int per = (N_EDGES + FILL_SLICES - 1) / FILL_SLICES;  // 25000
    int e0 = slice * per;
    int e1 = min(N_EDGES, e0 + per);
    for (int e = e0 + (int)threadIdx.x; e < e1; e += 256) {
        int c = col32[e];
        if (c >= lo && c < hi) {
            int r = row32[e];
            int p = atomicAdd(&cursor[c], 1);
            csr_src[p] = r;
        }
    }
}

// W1 [500,256] f32 -> W1s bf16 swizzled [ks=16][n=256][kk=32], K zero-padded to 512
__global__ void k_wconv1(const float* W1, u16* W1s) {
    int idx = blockIdx.x * 256 + threadIdx.x;
    if (idx >= 16 * 256 * 32) return;
    int ks = idx / (256 * 32);
    int rem = idx % (256 * 32);
    int n = rem / 32, kk = rem % 32;
    int k = ks * 32 + kk;
    float v = (k < 500) ? W1[k * 256 + n] : 0.0f;
    W1s[idx] = f2bf(v);
}

// W2 [256,64] f32 -> W2s bf16 swizzled [ks=8][n=64][kk=32]
__global__ void k_wconv2(const float* W2, u16* W2s) {
    int idx = blockIdx.x * 256 + threadIdx.x;
    if (idx >= 8 * 64 * 32) return;
    int ks = idx / (64 * 32);
    int rem = idx % (64 * 32);
    int n = rem / 32, kk = rem % 32;
    int k = ks * 32 + kk;
    W2s[idx] = f2bf(W2[k * 64 + n]);
}

// Fused MLP: per block 64 rows. GEMM1 (K=500->512, N=256, bf16 MFMA) -> relu -> LDS
// -> GEMM2 (K=256, N=64) -> h_bf, zs0 = dinv*h
__global__ __launch_bounds__(256) void k_mlp(
    const float* __restrict__ x, const u16* __restrict__ W1s,
    const float* __restrict__ b1, const u16* __restrict__ W2s,
    const float* __restrict__ b2, const float* __restrict__ dinv,
    u16* __restrict__ h_bf, u16* __restrict__ zs0) {

    __shared__ u16 A_lds[64 * APAD];
    __shared__ u16 B_lds[256 * APAD];
    __shared__ u16 H_lds[64 * 264];

    int t = threadIdx.x;
    int lane = t & 63, w = t >> 6;
    int m0 = blockIdx.x * 64;
    int cl = lane & 15, hi = lane >> 4;

    f32x4 acc[16];
    f32x4 zero = {0.f, 0.f, 0.f, 0.f};
#pragma unroll
    for (int i = 0; i < 16; ++i) acc[i] = zero;

    for (int ks = 0; ks < 16; ++ks) {
        {
            int r = t >> 2, k0 = (t & 3) * 8;
            int grow = m0 + r;
            int gk = ks * 32 + k0;
            u16 tmp[8];
            if (grow < N_NODES && gk + 8 <= 500) {
                const float4* p = (const float4*)(x + (size_t)grow * 500 + gk);
                float4 f0 = p[0], f1 = p[1];
                tmp[0] = f2bf(f0.x); tmp[1] = f2bf(f0.y);
                tmp[2] = f2bf(f0.z); tmp[3] = f2bf(f0.w);
                tmp[4] = f2bf(f1.x); tmp[5] = f2bf(f1.y);
                tmp[6] = f2bf(f1.z); tmp[7] = f2bf(f1.w);
            } else {
#pragma unroll
                for (int i = 0; i < 8; ++i) {
                    int k = gk + i;
                    float v = (grow < N_NODES && k < 500) ? x[(size_t)grow * 500 + k] : 0.0f;
                    tmp[i] = f2bf(v);
                }
            }
            uint4 u;
            u.x = (unsigned)tmp[0] | ((unsigned)tmp[1] << 16);
            u.y = (unsigned)tmp[2] | ((unsigned)tmp[3] << 16);
            u.z = (unsigned)tmp[4] | ((unsigned)tmp[5] << 16);
            u.w = (unsigned)tmp[6] | ((unsigned)tmp[7] << 16);
            *(uint4*)&A_lds[r * APAD + k0] = u;
        }
        {
            const uint4* s4 = (const uint4*)(W1s + ks * 256 * 32 + t * 32);
            uint4 a0 = s4[0], a1 = s4[1], a2 = s4[2], a3 = s4[3];
            uint4* dst = (uint4*)&B_lds[t * APAD];
            dst[0] = a0; dst[1] = a1; dst[2] = a2; dst[3] = a3;
        }
        __syncthreads();
        bf16x8 a = *reinterpret_cast<const bf16x8*>(&A_lds[(w * 16 + cl) * APAD + 8 * hi]);
#pragma unroll
        for (int nt = 0; nt < 16; ++nt) {
            bf16x8 b = *reinterpret_cast<const bf16x8*>(&B_lds[(nt * 16 + cl) * APAD + 8 * hi]);
            acc[nt] = __builtin_amdgcn_mfma_f32_16x16x32_bf16(a, b, acc[nt], 0, 0, 0);
        }
        __syncthreads();
    }

#pragma unroll
    for (int nt = 0; nt < 16; ++nt) {
        int col = nt * 16 + cl;
        float bb = b1[col];
#pragma unroll
        for (int r = 0; r < 4; ++r) {
            int row = w * 16 + hi * 4 + r;
            float v = acc[nt][r] + bb;
            v = fmaxf(v, 0.0f);
            H_lds[row * 264 + col] = f2bf(v);
        }
    }
    __syncthreads();

    f32x4 acc2[4];
#pragma unroll
    for (int i = 0; i < 4; ++i) acc2[i] = zero;
#pragma unroll
    for (int ks = 0; ks < 8; ++ks) {
        bf16x8 a = *reinterpret_cast<const bf16x8*>(&H_lds[(w * 16 + cl) * 264 + ks * 32 + 8 * hi]);
#pragma unroll
        for (int nt = 0; nt < 4; ++nt) {
            bf16x8 b = *reinterpret_cast<const bf16x8*>(W2s + (ks * 64 + nt * 16 + cl) * 32 + 8 * hi);
            acc2[nt] = __builtin_amdgcn_mfma_f32_16x16x32_bf16(a, b, acc2[nt], 0, 0, 0);
        }
    }
#pragma unroll
    for (int nt = 0; nt < 4; ++nt) {
        int col = nt * 16 + cl;
        float bb = b2[col];
#pragma unroll
        for (int r = 0; r < 4; ++r) {
            int row = m0 + w * 16 + hi * 4 + r;
            if (row < N_NODES) {
                float v = acc2[nt][r] + bb;
                h_bf[(size_t)row * 64 + col] = f2bf(v);
                zs0[(size_t)row * 64 + col] = f2bf(dinv[row] * v);
            }
        }
    }
}

// Propagation v3: one wave per node. Lane = (edge-slot g = lane>>3,
// channel-group c = lane&7 -> channels 8c..8c+7, 16B). One dwordx4 gather
// covers 8 edges per VMEM instruction (1KB/wave); unroll x2 -> 2KB in flight.
// z_new[v] = 0.9*dinv[v]*(sum_src zs[src] + zs[v]) + 0.1*h[v],  zs = dinv.*z
__global__ __launch_bounds__(256) void k_prop3(
    const u16* __restrict__ zs_in, const u16* __restrict__ h_bf,
    const float* __restrict__ dinv, const int* __restrict__ ptr,
    const int* __restrict__ csr_src, u16* __restrict__ zs_out,
    float* __restrict__ out, int last) {

    int lane = threadIdx.x & 63;
    int g = lane >> 3;   // edge slot 0..7
    int c = lane & 7;    // channels 8c..8c+7
    int v = blockIdx.x * 4 + (threadIdx.x >> 6);
    if (v >= N_NODES) return;
    int s0 = ptr[v], s1 = ptr[v + 1];

    float a0 = 0.f, a1 = 0.f, a2 = 0.f, a3 = 0.f;
    float a4 = 0.f, a5 = 0.f, a6 = 0.f, a7 = 0.f;
    float b0 = 0.f, b1 = 0.f, b2 = 0.f, b3 = 0.f;
    float b4 = 0.f, b5 = 0.f, b6 = 0.f, b7 = 0.f;

    for (int base = s0; base < s1; base += 64) {
        int nwin = min(64, s1 - base);
        int ei = base + lane;
        int sv = (ei < s1) ? csr_src[ei] : v;   // fallback: safe address
        int j = 0;
        for (; j + 16 <= nwin; j += 16) {
            int u0 = __shfl(sv, j + g, 64);
            int u1 = __shfl(sv, j + 8 + g, 64);
            uint4 q0 = *(const uint4*)(zs_in + (size_t)u0 * 64 + c * 8);
            uint4 q1 = *(const uint4*)(zs_in + (size_t)u1 * 64 + c * 8);
            a0 += bf2f_lo(q0.x); a1 += bf2f_hi(q0.x);
            a2 += bf2f_lo(q0.y); a3 += bf2f_hi(q0.y);
            a4 += bf2f_lo(q0.z); a5 += bf2f_hi(q0.z);
            a6 += bf2f_lo(q0.w); a7 += bf2f_hi(q0.w);
            b0 += bf2f_lo(q1.x); b1 += bf2f_hi(q1.x);
            b2 += bf2f_lo(q1.y); b3 += bf2f_hi(q1.y);
            b4 += bf2f_lo(q1.z); b5 += bf2f_hi(q1.z);
            b6 += bf2f_lo(q1.w); b7 += bf2f_hi(q1.w);
        }
        for (; j < nwin; j += 8) {
            int idx = j + g;
            int u = __shfl(sv, idx, 64);  // idx<=63; invalid lanes hold v (safe)
            uint4 q = *(const uint4*)(zs_in + (size_t)u * 64 + c * 8);
            if (idx < nwin) {
                a0 += bf2f_lo(q.x); a1 += bf2f_hi(q.x);
                a2 += bf2f_lo(q.y); a3 += bf2f_hi(q.y);
                a4 += bf2f_lo(q.z); a5 += bf2f_hi(q.z);
                a6 += bf2f_lo(q.w); a7 += bf2f_hi(q.w);
            }
        }
    }
    a0 += b0; a1 += b1; a2 += b2; a3 += b3;
    a4 += b4; a5 += b5; a6 += b6; a7 += b7;
    // reduce across the 8 edge slots (lane bits 3,4,5)
#pragma unroll
    for (int off = 8; off <= 32; off <<= 1) {
        a0 += __shfl_xor(a0, off, 64); a1 += __shfl_xor(a1, off, 64);
        a2 += __shfl_xor(a2, off, 64); a3 += __shfl_xor(a3, off, 64);
        a4 += __shfl_xor(a4, off, 64); a5 += __shfl_xor(a5, off, 64);
        a6 += __shfl_xor(a6, off, 64); a7 += __shfl_xor(a7, off, 64);
    }

    float dv = dinv[v];
    uint4 qs = *(const uint4*)(zs_in + (size_t)v * 64 + c * 8);
    uint4 qh = *(const uint4*)(h_bf + (size_t)v * 64 + c * 8);
    float z0 = (1.0f - ALPHA) * dv * (a0 + bf2f_lo(qs.x)) + ALPHA * bf2f_lo(qh.x);
    float z1 = (1.0f - ALPHA) * dv * (a1 + bf2f_hi(qs.x)) + ALPHA * bf2f_hi(qh.x);
    float z2 = (1.0f - ALPHA) * dv * (a2 + bf2f_lo(qs.y)) + ALPHA * bf2f_lo(qh.y);
    float z3 = (1.0f - ALPHA) * dv * (a3 + bf2f_hi(qs.y)) + ALPHA * bf2f_hi(qh.y);
    float z4 = (1.0f - ALPHA) * dv * (a4 + bf2f_lo(qs.z)) + ALPHA * bf2f_lo(qh.z);
    float z5 = (1.0f - ALPHA) * dv * (a5 + bf2f_hi(qs.z)) + ALPHA * bf2f_hi(qh.z);
    float z6 = (1.0f - ALPHA) * dv * (a6 + bf2f_lo(qs.w)) + ALPHA * bf2f_lo(qh.w);
    float z7 = (1.0f - ALPHA) * dv * (a7 + bf2f_hi(qs.w)) + ALPHA * bf2f_hi(qh.w);

    if (!last) {
        if (g == 0) {
            uint4 o;
            o.x = (unsigned)f2bf(dv * z0) | ((unsigned)f2bf(dv * z1) << 16);
            o.y = (unsigned)f2bf(dv * z2) | ((unsigned)f2bf(dv * z3) << 16);
            o.z = (unsigned)f2bf(dv * z4) | ((unsigned)f2bf(dv * z5) << 16);
            o.w = (unsigned)f2bf(dv * z6) | ((unsigned)f2bf(dv * z7) << 16);
            *(uint4*)(zs_out + (size_t)v * 64 + c * 8) = o;
        }
    } else {
        float m = fmaxf(fmaxf(fmaxf(z0, z1), fmaxf(z2, z3)),
                        fmaxf(fmaxf(z4, z5), fmaxf(z6, z7)));
#pragma unroll
        for (int off = 1; off <= 4; off <<= 1) m = fmaxf(m, __shfl_xor(m, off, 64));
        float p = expf(z0 - m) + expf(z1 - m) + expf(z2 - m) + expf(z3 - m)
                + expf(z4 - m) + expf(z5 - m) + expf(z6 - m) + expf(z7 - m);
#pragma unroll
        for (int off = 1; off <= 4; off <<= 1) p += __shfl_xor(p, off, 64);
        float ls = logf(p);
        if (g == 0) {
            float4 o1 = {z0 - m - ls, z1 - m - ls, z2 - m - ls, z3 - m - ls};
            float4 o2 = {z4 - m - ls, z5 - m - ls, z6 - m - ls, z7 - m - ls};
            *(float4*)(out + (size_t)v * 64 + c * 8) = o1;
            *(float4*)(out + (size_t)v * 64 + c * 8 + 4) = o2;
        }
    }
}

extern "C" void kernel_launch(void* const* d_in, const int* in_sizes, int n_in,
                              void* d_out, int out_size, void* d_ws, size_t ws_size,
                              hipStream_t stream) {
    const float* x  = (const float*)d_in[0];
    const void* edges = d_in[1];
    const float* W1 = (const float*)d_in[2];
    const float* b1 = (const float*)d_in[3];
    const float* W2 = (const float*)d_in[4];
    const float* b2 = (const float*)d_in[5];
    float* out = (float*)d_out;

    char* ws = (char*)d_ws;
    size_t off = 0;
    auto alloc = [&](size_t bytes) -> void* {
        void* p = ws + off;
        off = (off + bytes + 255) & ~(size_t)255;
        return p;
    };
    int*   flag    = (int*)alloc(4);
    int*   deg     = (int*)alloc((size_t)N_NODES * 4);
    float* dinv    = (float*)alloc((size_t)N_NODES * 4);
    int*   ptr     = (int*)alloc((size_t)(N_NODES + 1) * 4);
    int*   cursor  = (int*)alloc((size_t)N_NODES * 4);
    int*   bsum    = (int*)alloc((size_t)SCAN_NB * 4);
    int*   boff    = (int*)alloc((size_t)SCAN_NB * 4);
    int*   csr_src = (int*)alloc((size_t)N_EDGES * 4);
    u16*   W1s     = (u16*)alloc((size_t)16 * 256 * 32 * 2);
    u16*   W2s     = (u16*)alloc((size_t)8 * 64 * 32 * 2);
    u16*   h_bf    = (u16*)alloc((size_t)N_NODES * 64 * 2);
    u16*   zsA     = (u16*)alloc((size_t)N_NODES * 64 * 2);
    int*   row32   = (int*)alloc((size_t)N_EDGES * 4);  // aliased as zsB after fill
    int*   col32   = (int*)alloc((size_t)N_EDGES * 4);
    u16*   zsB     = (u16*)row32;  // row32 dead after k_fill2; N_EDGES*4 == N*64*2

    hipMemsetAsync(deg, 0, (size_t)N_NODES * 4, stream);
    k_detect<<<1, 64, 0, stream>>>((const unsigned int*)edges, flag);
    k_convert_count<<<(N_EDGES + 255) / 256, 256, 0, stream>>>(edges, flag, row32, col32, deg);
    k_scan_part<<<SCAN_NB, SCAN_BS, 0, stream>>>(deg, ptr, bsum);
    k_scan_bsum<<<1, 256, 0, stream>>>(bsum, boff, ptr);
    k_scan_apply<<<SCAN_NB, SCAN_BS, 0, stream>>>(deg, boff, ptr, cursor, dinv);
    k_fill2<<<8 * FILL_SLICES, 256, 0, stream>>>(row32, col32, cursor, csr_src);
    k_wconv1<<<(16 * 256 * 32 + 255) / 256, 256, 0, stream>>>(W1, W1s);
    k_wconv2<<<(8 * 64 * 32 + 255) / 256, 256, 0, stream>>>(W2, W2s);
    k_mlp<<<(N_NODES + 63) / 64, 256, 0, stream>>>(x, W1s, b1, W2s, b2, dinv, h_bf, zsA);

    const u16* zin = zsA;
    u16* zout = zsB;
    for (int k = 0; k < KITER; ++k) {
        int last = (k == KITER - 1) ? 1 : 0;
        k_prop3<<<(N_NODES + 3) / 4, 256, 0, stream>>>(zin, h_bf, dinv, ptr, csr_src,
                                                       zout, out, last);
        u16* t = zout;
        zout = (u16*)zin;
        zin = t;
    }
}

// Round 4
// 952.216 us; speedup vs baseline: 1.5742x; 1.0080x over previous
//
#include <hip/hip_runtime.h>
#include <hip/hip_bf16.h>

#define N_NODES 100000
#define N_EDGES 3200000
#define KITER   10
#define ALPHA   0.1f

#define SCAN_BS 512
#define SCAN_NB ((N_NODES + SCAN_BS - 1) / SCAN_BS)   // 196

typedef __attribute__((ext_vector_type(4))) float f32x4;
typedef __attribute__((ext_vector_type(8))) short bf16x8;
typedef unsigned short u16;

__device__ inline float bf2f(u16 u) {
    unsigned int x = ((unsigned int)u) << 16;
    return __uint_as_float(x);
}
__device__ inline float bf2f_lo(unsigned int w) { return __uint_as_float(w << 16); }
__device__ inline float bf2f_hi(unsigned int w) { return __uint_as_float(w & 0xffff0000u); }
__device__ inline u16 f2bf(float f) {
    __hip_bfloat16 h = __float2bfloat16(f);
    return *reinterpret_cast<u16*>(&h);
}
__device__ inline bf16x8 cvt8(float4 lo, float4 hi) {
    bf16x8 r;
    r[0] = (short)f2bf(lo.x); r[1] = (short)f2bf(lo.y);
    r[2] = (short)f2bf(lo.z); r[3] = (short)f2bf(lo.w);
    r[4] = (short)f2bf(hi.x); r[5] = (short)f2bf(hi.y);
    r[6] = (short)f2bf(hi.z); r[7] = (short)f2bf(hi.w);
    return r;
}

// edge_index may arrive as int64 (reference dtype) or int32 (harness policy).
__global__ void k_detect(const unsigned int* e32, int* flag) {
    if (threadIdx.x == 0) {
        int is64 = 1;
        for (int i = 0; i < 64; ++i)
            if (e32[2 * i + 1] != 0u) { is64 = 0; break; }
        *flag = is64;
    }
}

__device__ inline int eidx(const void* p, int is64, int i) {
    if (is64) return (int)((const long long*)p)[i];
    return ((const int*)p)[i];
}

// convert edges to int32 row/col arrays AND count in-degrees (fused)
__global__ void k_convert_count(const void* edges, const int* flag,
                                int* row32, int* col32, int* deg) {
    int i = blockIdx.x * 256 + threadIdx.x;
    if (i >= N_EDGES) return;
    int is64 = *flag;
    int r = eidx(edges, is64, i);
    int c = eidx(edges, is64, N_EDGES + i);
    row32[i] = r;
    col32[i] = c;
    atomicAdd(&deg[c], 1);
}

// ---- two-level scan: local scan -> scan of block sums -> apply ----
__global__ __launch_bounds__(SCAN_BS) void k_scan_part(const int* __restrict__ deg,
                                                       int* __restrict__ ptr,
                                                       int* __restrict__ bsum) {
    __shared__ int lds[SCAN_BS];
    int t = threadIdx.x;
    int idx = blockIdx.x * SCAN_BS + t;
    int s = (idx < N_NODES) ? deg[idx] : 0;
    lds[t] = s;
    __syncthreads();
#pragma unroll
    for (int off = 1; off < SCAN_BS; off <<= 1) {
        int v = (t >= off) ? lds[t - off] : 0;
        __syncthreads();
        lds[t] += v;
        __syncthreads();
    }
    if (idx < N_NODES) ptr[idx] = lds[t] - s;     // exclusive local
    if (t == SCAN_BS - 1) bsum[blockIdx.x] = lds[t];
}

__global__ __launch_bounds__(256) void k_scan_bsum(const int* __restrict__ bsum,
                                                   int* __restrict__ boff,
                                                   int* __restrict__ ptr) {
    __shared__ int lds[256];
    int t = threadIdx.x;
    int s = (t < SCAN_NB) ? bsum[t] : 0;
    lds[t] = s;
    __syncthreads();
#pragma unroll
    for (int off = 1; off < 256; off <<= 1) {
        int v = (t >= off) ? lds[t - off] : 0;
        __syncthreads();
        lds[t] += v;
        __syncthreads();
    }
    if (t < SCAN_NB) boff[t] = lds[t] - s;        // exclusive
    if (t == 255) ptr[N_NODES] = lds[t];          // total (== N_EDGES)
}

__global__ __launch_bounds__(SCAN_BS) void k_scan_apply(const int* __restrict__ deg,
                                                        const int* __restrict__ boff,
                                                        int* __restrict__ ptr,
                                                        int* __restrict__ cursor,
                                                        float* __restrict__ dinv) {
    int idx = blockIdx.x * SCAN_BS + threadIdx.x;
    if (idx >= N_NODES) return;
    int p = ptr[idx] + boff[blockIdx.x];
    ptr[idx] = p;
    cursor[idx] = p;
    dinv[idx] = rsqrtf((float)(deg[idx] + 1));    // +1 self loop
}

// XCD-ownership fill: grp = blockIdx%8 owns target range [grp*12500, +12500).
#define FILL_SLICES 128
__global__ __launch_bounds__(256) void k_fill2(const int* __restrict__ row32,
                                               const int* __restrict__ col32,
                                               int* cursor, int* __restrict__ csr_src) {
    int b = blockIdx.x;
    int grp = b & 7;
    int slice = b >> 3;
    int lo = grp * 12500, hi = lo + 12500;
    const int per = (N_EDGES + FILL_SLICES - 1) / FILL_SLICES;  // 25000
    int e0 = slice * per;
    int e1 = min(N_EDGES, e0 + per);
    for (int e = e0 + (int)threadIdx.x; e < e1; e += 256) {
        int c = col32[e];
        if (c >= lo && c < hi) {
            int r = row32[e];
            int p = atomicAdd(&cursor[c], 1);
            csr_src[p] = r;
        }
    }
}

// W1 [500,256] f32 -> W1s bf16 swizzled [ks=16][n=256][kk=32], K zero-padded to 512
__global__ void k_wconv1(const float* W1, u16* W1s) {
    int idx = blockIdx.x * 256 + threadIdx.x;
    if (idx >= 16 * 256 * 32) return;
    int ks = idx / (256 * 32);
    int rem = idx % (256 * 32);
    int n = rem / 32, kk = rem % 32;
    int k = ks * 32 + kk;
    float v = (k < 500) ? W1[k * 256 + n] : 0.0f;
    W1s[idx] = f2bf(v);
}

// W2 [256,64] f32 -> W2s bf16 swizzled [ks=8][n=64][kk=32]
__global__ void k_wconv2(const float* W2, u16* W2s) {
    int idx = blockIdx.x * 256 + threadIdx.x;
    if (idx >= 8 * 64 * 32) return;
    int ks = idx / (64 * 32);
    int rem = idx % (64 * 32);
    int n = rem / 32, kk = rem % 32;
    int k = ks * 32 + kk;
    W2s[idx] = f2bf(W2[k * 64 + n]);
}

// Fused MLP v2: barrier-free MFMA K-loop.
// Block = 256 threads = 4 waves; wave w owns 32 rows (2 row-tiles of 16).
// A (x) read DIRECT from global (f32 -> bf16 in reg, 1-step prefetch).
// B (W1s) read DIRECT from global: 16B frags, L2-resident panel.
// LDS used only for H (relu output, k-transpose for GEMM2) and for packing
// the epilogue into coalesced 64B stores. Only 2 barriers in the kernel.
#define MLP_ROWS 128
#define HSTR 264    // u16 stride for H rows (132 dwords = 4 mod 32 banks)
#define H2STR 72    // u16 stride for pack buffer (16B-aligned rows)

__global__ __launch_bounds__(256, 2) void k_mlp(
    const float* __restrict__ x, const u16* __restrict__ W1s,
    const float* __restrict__ b1, const u16* __restrict__ W2s,
    const float* __restrict__ b2, const float* __restrict__ dinv,
    u16* __restrict__ h_bf, u16* __restrict__ zs0) {

    __shared__ u16 H_lds[MLP_ROWS * HSTR];   // 67584 B

    int t = threadIdx.x;
    int lane = t & 63, w = t >> 6;
    int m0 = blockIdx.x * MLP_ROWS;
    int cl = lane & 15, hi = lane >> 4;

    int row0 = m0 + w * 32 + cl;
    int row1 = row0 + 16;
    int row0c = min(row0, N_NODES - 1);
    int row1c = min(row1, N_NODES - 1);
    const float* xr0 = x + (size_t)row0c * 500 + 8 * hi;
    const float* xr1 = x + (size_t)row1c * 500 + 8 * hi;

    f32x4 acc0[16], acc1[16];
    f32x4 zero = {0.f, 0.f, 0.f, 0.f};
#pragma unroll
    for (int i = 0; i < 16; ++i) { acc0[i] = zero; acc1[i] = zero; }

    // prologue: load ks=0
    float4 c0lo = *(const float4*)(xr0);
    float4 c0hi = *(const float4*)(xr0 + 4);
    float4 c1lo = *(const float4*)(xr1);
    float4 c1hi = *(const float4*)(xr1 + 4);

    const u16* bbase = W1s + cl * 32 + 8 * hi;

    for (int ks = 0; ks < 15; ++ks) {
        float4 n0lo, n0hi, n1lo, n1hi;
        if (ks < 14) {
            const float* p0 = xr0 + (ks + 1) * 32;
            const float* p1 = xr1 + (ks + 1) * 32;
            n0lo = *(const float4*)(p0);
            n0hi = *(const float4*)(p0 + 4);
            n1lo = *(const float4*)(p1);
            n1hi = *(const float4*)(p1 + 4);
        }
        bf16x8 af0 = cvt8(c0lo, c0hi);
        bf16x8 af1 = cvt8(c1lo, c1hi);
        const u16* bp = bbase + ks * 8192;
#pragma unroll
        for (int nt = 0; nt < 16; ++nt) {
            bf16x8 b = *reinterpret_cast<const bf16x8*>(bp + nt * 512);
            acc0[nt] = __builtin_amdgcn_mfma_f32_16x16x32_bf16(af0, b, acc0[nt], 0, 0, 0);
            acc1[nt] = __builtin_amdgcn_mfma_f32_16x16x32_bf16(af1, b, acc1[nt], 0, 0, 0);
        }
        if (ks < 14) { c0lo = n0lo; c0hi = n0hi; c1lo = n1lo; c1hi = n1hi; }
    }
    // peeled ks=15: k = 480 + 8*hi + j, guard k<500 (zero-pad + OOB safety)
    {
        int kb = 480 + 8 * hi;
        float t0[8], t1[8];
#pragma unroll
        for (int j = 0; j < 8; ++j) {
            int k = kb + j;
            t0[j] = (k < 500) ? xr0[15 * 32 + j] : 0.0f;
            t1[j] = (k < 500) ? xr1[15 * 32 + j] : 0.0f;
        }
        bf16x8 af0, af1;
#pragma unroll
        for (int j = 0; j < 8; ++j) { af0[j] = (short)f2bf(t0[j]); af1[j] = (short)f2bf(t1[j]); }
        const u16* bp = bbase + 15 * 8192;
#pragma unroll
        for (int nt = 0; nt < 16; ++nt) {
            bf16x8 b = *reinterpret_cast<const bf16x8*>(bp + nt * 512);
            acc0[nt] = __builtin_amdgcn_mfma_f32_16x16x32_bf16(af0, b, acc0[nt], 0, 0, 0);
            acc1[nt] = __builtin_amdgcn_mfma_f32_16x16x32_bf16(af1, b, acc1[nt], 0, 0, 0);
        }
    }

    // epilogue 1: +b1, relu -> H_lds (each wave writes ONLY its own 32 rows,
    // and GEMM2 reads only those rows -> no barrier needed before GEMM2)
    {
        int rl0 = w * 32 + hi * 4;
#pragma unroll
        for (int nt = 0; nt < 16; ++nt) {
            int col = nt * 16 + cl;
            float bb = b1[col];
#pragma unroll
            for (int r = 0; r < 4; ++r) {
                float v0 = fmaxf(acc0[nt][r] + bb, 0.0f);
                float v1 = fmaxf(acc1[nt][r] + bb, 0.0f);
                H_lds[(rl0 + r) * HSTR + col] = f2bf(v0);
                H_lds[(rl0 + 16 + r) * HSTR + col] = f2bf(v1);
            }
        }
    }

    // GEMM2: H[32 rows x 256] @ W2s[256 x 64], B direct from global (L2)
    f32x4 acc20[4], acc21[4];
#pragma unroll
    for (int i = 0; i < 4; ++i) { acc20[i] = zero; acc21[i] = zero; }
    int rA0 = w * 32 + cl;
#pragma unroll
    for (int ks2 = 0; ks2 < 8; ++ks2) {
        bf16x8 af0 = *reinterpret_cast<const bf16x8*>(&H_lds[rA0 * HSTR + ks2 * 32 + 8 * hi]);
        bf16x8 af1 = *reinterpret_cast<const bf16x8*>(&H_lds[(rA0 + 16) * HSTR + ks2 * 32 + 8 * hi]);
#pragma unroll
        for (int nt = 0; nt < 4; ++nt) {
            bf16x8 b = *reinterpret_cast<const bf16x8*>(W2s + (ks2 * 64 + nt * 16 + cl) * 32 + 8 * hi);
            acc20[nt] = __builtin_amdgcn_mfma_f32_16x16x32_bf16(af0, b, acc20[nt], 0, 0, 0);
            acc21[nt] = __builtin_amdgcn_mfma_f32_16x16x32_bf16(af1, b, acc21[nt], 0, 0, 0);
        }
    }
    __syncthreads();   // all waves done reading H_lds; safe to overwrite as H2

    // epilogue 2: +b2 -> pack buffer H2 (reuses H_lds memory)
    u16* H2 = H_lds;
    {
        int rl0 = w * 32 + hi * 4;
#pragma unroll
        for (int nt = 0; nt < 4; ++nt) {
            int col = nt * 16 + cl;
            float bb = b2[col];
#pragma unroll
            for (int r = 0; r < 4; ++r) {
                H2[(rl0 + r) * H2STR + col] = f2bf(acc20[nt][r] + bb);
                H2[(rl0 + 16 + r) * H2STR + col] = f2bf(acc21[nt][r] + bb);
            }
        }
    }
    __syncthreads();

    // pack & store: thread t handles half a row (32 u16 = 64B), coalesced
    {
        int rl = t >> 1, half = t & 1;
        int grow = m0 + rl;
        if (grow < N_NODES) {
            float dv = dinv[grow];
            const uint4* src = (const uint4*)&H2[rl * H2STR + half * 32];
            uint4 q0 = src[0], q1 = src[1], q2 = src[2], q3 = src[3];
            uint4 hq[4] = {q0, q1, q2, q3};
            uint4 zq[4];
#pragma unroll
            for (int i = 0; i < 4; ++i) {
                unsigned int* hw = (unsigned int*)&hq[i];
                unsigned int* zw = (unsigned int*)&zq[i];
#pragma unroll
                for (int jj = 0; jj < 4; ++jj) {
                    float lo = dv * bf2f_lo(hw[jj]);
                    float hi2 = dv * bf2f_hi(hw[jj]);
                    zw[jj] = (unsigned)f2bf(lo) | ((unsigned)f2bf(hi2) << 16);
                }
            }
            uint4* hd = (uint4*)(h_bf + (size_t)grow * 64 + half * 32);
            uint4* zd = (uint4*)(zs0 + (size_t)grow * 64 + half * 32);
            hd[0] = hq[0]; hd[1] = hq[1]; hd[2] = hq[2]; hd[3] = hq[3];
            zd[0] = zq[0]; zd[1] = zq[1]; zd[2] = zq[2]; zd[3] = zq[3];
        }
    }
}

// Propagation v3 (unchanged): one wave per node, dwordx4 gathers of 8 edges.
__global__ __launch_bounds__(256) void k_prop3(
    const u16* __restrict__ zs_in, const u16* __restrict__ h_bf,
    const float* __restrict__ dinv, const int* __restrict__ ptr,
    const int* __restrict__ csr_src, u16* __restrict__ zs_out,
    float* __restrict__ out, int last) {

    int lane = threadIdx.x & 63;
    int g = lane >> 3;   // edge slot 0..7
    int c = lane & 7;    // channels 8c..8c+7
    int v = blockIdx.x * 4 + (threadIdx.x >> 6);
    if (v >= N_NODES) return;
    int s0 = ptr[v], s1 = ptr[v + 1];

    float a0 = 0.f, a1 = 0.f, a2 = 0.f, a3 = 0.f;
    float a4 = 0.f, a5 = 0.f, a6 = 0.f, a7 = 0.f;
    float b0 = 0.f, b1 = 0.f, b2 = 0.f, b3 = 0.f;
    float b4 = 0.f, b5 = 0.f, b6 = 0.f, b7 = 0.f;

    for (int base = s0; base < s1; base += 64) {
        int nwin = min(64, s1 - base);
        int ei = base + lane;
        int sv = (ei < s1) ? csr_src[ei] : v;   // fallback: safe address
        int j = 0;
        for (; j + 16 <= nwin; j += 16) {
            int u0 = __shfl(sv, j + g, 64);
            int u1 = __shfl(sv, j + 8 + g, 64);
            uint4 q0 = *(const uint4*)(zs_in + (size_t)u0 * 64 + c * 8);
            uint4 q1 = *(const uint4*)(zs_in + (size_t)u1 * 64 + c * 8);
            a0 += bf2f_lo(q0.x); a1 += bf2f_hi(q0.x);
            a2 += bf2f_lo(q0.y); a3 += bf2f_hi(q0.y);
            a4 += bf2f_lo(q0.z); a5 += bf2f_hi(q0.z);
            a6 += bf2f_lo(q0.w); a7 += bf2f_hi(q0.w);
            b0 += bf2f_lo(q1.x); b1 += bf2f_hi(q1.x);
            b2 += bf2f_lo(q1.y); b3 += bf2f_hi(q1.y);
            b4 += bf2f_lo(q1.z); b5 += bf2f_hi(q1.z);
            b6 += bf2f_lo(q1.w); b7 += bf2f_hi(q1.w);
        }
        for (; j < nwin; j += 8) {
            int idx = j + g;
            int u = __shfl(sv, idx, 64);  // idx<=63; invalid lanes hold v (safe)
            uint4 q = *(const uint4*)(zs_in + (size_t)u * 64 + c * 8);
            if (idx < nwin) {
                a0 += bf2f_lo(q.x); a1 += bf2f_hi(q.x);
                a2 += bf2f_lo(q.y); a3 += bf2f_hi(q.y);
                a4 += bf2f_lo(q.z); a5 += bf2f_hi(q.z);
                a6 += bf2f_lo(q.w); a7 += bf2f_hi(q.w);
            }
        }
    }
    a0 += b0; a1 += b1; a2 += b2; a3 += b3;
    a4 += b4; a5 += b5; a6 += b6; a7 += b7;
#pragma unroll
    for (int off = 8; off <= 32; off <<= 1) {
        a0 += __shfl_xor(a0, off, 64); a1 += __shfl_xor(a1, off, 64);
        a2 += __shfl_xor(a2, off, 64); a3 += __shfl_xor(a3, off, 64);
        a4 += __shfl_xor(a4, off, 64); a5 += __shfl_xor(a5, off, 64);
        a6 += __shfl_xor(a6, off, 64); a7 += __shfl_xor(a7, off, 64);
    }

    float dv = dinv[v];
    uint4 qs = *(const uint4*)(zs_in + (size_t)v * 64 + c * 8);
    uint4 qh = *(const uint4*)(h_bf + (size_t)v * 64 + c * 8);
    float z0 = (1.0f - ALPHA) * dv * (a0 + bf2f_lo(qs.x)) + ALPHA * bf2f_lo(qh.x);
    float z1 = (1.0f - ALPHA) * dv * (a1 + bf2f_hi(qs.x)) + ALPHA * bf2f_hi(qh.x);
    float z2 = (1.0f - ALPHA) * dv * (a2 + bf2f_lo(qs.y)) + ALPHA * bf2f_lo(qh.y);
    float z3 = (1.0f - ALPHA) * dv * (a3 + bf2f_hi(qs.y)) + ALPHA * bf2f_hi(qh.y);
    float z4 = (1.0f - ALPHA) * dv * (a4 + bf2f_lo(qs.z)) + ALPHA * bf2f_lo(qh.z);
    float z5 = (1.0f - ALPHA) * dv * (a5 + bf2f_hi(qs.z)) + ALPHA * bf2f_hi(qh.z);
    float z6 = (1.0f - ALPHA) * dv * (a6 + bf2f_lo(qs.w)) + ALPHA * bf2f_lo(qh.w);
    float z7 = (1.0f - ALPHA) * dv * (a7 + bf2f_hi(qs.w)) + ALPHA * bf2f_hi(qh.w);

    if (!last) {
        if (g == 0) {
            uint4 o;
            o.x = (unsigned)f2bf(dv * z0) | ((unsigned)f2bf(dv * z1) << 16);
            o.y = (unsigned)f2bf(dv * z2) | ((unsigned)f2bf(dv * z3) << 16);
            o.z = (unsigned)f2bf(dv * z4) | ((unsigned)f2bf(dv * z5) << 16);
            o.w = (unsigned)f2bf(dv * z6) | ((unsigned)f2bf(dv * z7) << 16);
            *(uint4*)(zs_out + (size_t)v * 64 + c * 8) = o;
        }
    } else {
        float m = fmaxf(fmaxf(fmaxf(z0, z1), fmaxf(z2, z3)),
                        fmaxf(fmaxf(z4, z5), fmaxf(z6, z7)));
#pragma unroll
        for (int off = 1; off <= 4; off <<= 1) m = fmaxf(m, __shfl_xor(m, off, 64));
        float p = expf(z0 - m) + expf(z1 - m) + expf(z2 - m) + expf(z3 - m)
                + expf(z4 - m) + expf(z5 - m) + expf(z6 - m) + expf(z7 - m);
#pragma unroll
        for (int off = 1; off <= 4; off <<= 1) p += __shfl_xor(p, off, 64);
        float ls = logf(p);
        if (g == 0) {
            float4 o1 = {z0 - m - ls, z1 - m - ls, z2 - m - ls, z3 - m - ls};
            float4 o2 = {z4 - m - ls, z5 - m - ls, z6 - m - ls, z7 - m - ls};
            *(float4*)(out + (size_t)v * 64 + c * 8) = o1;
            *(float4*)(out + (size_t)v * 64 + c * 8 + 4) = o2;
        }
    }
}

extern "C" void kernel_launch(void* const* d_in, const int* in_sizes, int n_in,
                              void* d_out, int out_size, void* d_ws, size_t ws_size,
                              hipStream_t stream) {
    const float* x  = (const float*)d_in[0];
    const void* edges = d_in[1];
    const float* W1 = (const float*)d_in[2];
    const float* b1 = (const float*)d_in[3];
    const float* W2 = (const float*)d_in[4];
    const float* b2 = (const float*)d_in[5];
    float* out = (float*)d_out;

    char* ws = (char*)d_ws;
    size_t off = 0;
    auto alloc = [&](size_t bytes) -> void* {
        void* p = ws + off;
        off = (off + bytes + 255) & ~(size_t)255;
        return p;
    };
    int*   flag    = (int*)alloc(4);
    int*   deg     = (int*)alloc((size_t)N_NODES * 4);
    float* dinv    = (float*)alloc((size_t)N_NODES * 4);
    int*   ptr     = (int*)alloc((size_t)(N_NODES + 1) * 4);
    int*   cursor  = (int*)alloc((size_t)N_NODES * 4);
    int*   bsum    = (int*)alloc((size_t)SCAN_NB * 4);
    int*   boff    = (int*)alloc((size_t)SCAN_NB * 4);
    int*   csr_src = (int*)alloc((size_t)N_EDGES * 4);
    u16*   W1s     = (u16*)alloc((size_t)16 * 256 * 32 * 2);
    u16*   W2s     = (u16*)alloc((size_t)8 * 64 * 32 * 2);
    u16*   h_bf    = (u16*)alloc((size_t)N_NODES * 64 * 2);
    u16*   zsA     = (u16*)alloc((size_t)N_NODES * 64 * 2);
    int*   row32   = (int*)alloc((size_t)N_EDGES * 4);  // aliased as zsB after fill
    int*   col32   = (int*)alloc((size_t)N_EDGES * 4);
    u16*   zsB     = (u16*)row32;  // row32 dead after k_fill2; N_EDGES*4 == N*64*2

    hipMemsetAsync(deg, 0, (size_t)N_NODES * 4, stream);
    k_detect<<<1, 64, 0, stream>>>((const unsigned int*)edges, flag);
    k_convert_count<<<(N_EDGES + 255) / 256, 256, 0, stream>>>(edges, flag, row32, col32, deg);
    k_scan_part<<<SCAN_NB, SCAN_BS, 0, stream>>>(deg, ptr, bsum);
    k_scan_bsum<<<1, 256, 0, stream>>>(bsum, boff, ptr);
    k_scan_apply<<<SCAN_NB, SCAN_BS, 0, stream>>>(deg, boff, ptr, cursor, dinv);
    k_fill2<<<8 * FILL_SLICES, 256, 0, stream>>>(row32, col32, cursor, csr_src);
    k_wconv1<<<(16 * 256 * 32 + 255) / 256, 256, 0, stream>>>(W1, W1s);
    k_wconv2<<<(8 * 64 * 32 + 255) / 256, 256, 0, stream>>>(W2, W2s);
    k_mlp<<<(N_NODES + MLP_ROWS - 1) / MLP_ROWS, 256, 0, stream>>>(x, W1s, b1, W2s, b2,
                                                                   dinv, h_bf, zsA);

    const u16* zin = zsA;
    u16* zout = zsB;
    for (int k = 0; k < KITER; ++k) {
        int last = (k == KITER - 1) ? 1 : 0;
        k_prop3<<<(N_NODES + 3) / 4, 256, 0, stream>>>(zin, h_bf, dinv, ptr, csr_src,
                                                       zout, out, last);
        u16* t = zout;
        zout = (u16*)zin;
        zin = t;
    }
}

// Round 5
// 946.096 us; speedup vs baseline: 1.5844x; 1.0065x over previous
//
#include <hip/hip_runtime.h>
#include <hip/hip_bf16.h>

#define N_NODES 100000
#define N_EDGES 3200000
#define KITER   10
#define ALPHA   0.1f

#define SCAN_BS 512
#define SCAN_NB ((N_NODES + SCAN_BS - 1) / SCAN_BS)   // 196

typedef __attribute__((ext_vector_type(4))) float f32x4;
typedef __attribute__((ext_vector_type(8))) short bf16x8;
typedef unsigned short u16;

__device__ inline float bf2f(u16 u) {
    unsigned int x = ((unsigned int)u) << 16;
    return __uint_as_float(x);
}
__device__ inline float bf2f_lo(unsigned int w) { return __uint_as_float(w << 16); }
__device__ inline float bf2f_hi(unsigned int w) { return __uint_as_float(w & 0xffff0000u); }
__device__ inline u16 f2bf(float f) {
    __hip_bfloat16 h = __float2bfloat16(f);
    return *reinterpret_cast<u16*>(&h);
}
__device__ inline bf16x8 cvt8(float4 lo, float4 hi) {
    bf16x8 r;
    r[0] = (short)f2bf(lo.x); r[1] = (short)f2bf(lo.y);
    r[2] = (short)f2bf(lo.z); r[3] = (short)f2bf(lo.w);
    r[4] = (short)f2bf(hi.x); r[5] = (short)f2bf(hi.y);
    r[6] = (short)f2bf(hi.z); r[7] = (short)f2bf(hi.w);
    return r;
}

// edge_index may arrive as int64 (reference dtype) or int32 (harness policy).
__global__ void k_detect(const unsigned int* e32, int* flag) {
    if (threadIdx.x == 0) {
        int is64 = 1;
        for (int i = 0; i < 64; ++i)
            if (e32[2 * i + 1] != 0u) { is64 = 0; break; }
        *flag = is64;
    }
}

__device__ inline int eidx(const void* p, int is64, int i) {
    if (is64) return (int)((const long long*)p)[i];
    return ((const int*)p)[i];
}

// convert edges to int32 row/col arrays AND count in-degrees (fused)
__global__ void k_convert_count(const void* edges, const int* flag,
                                int* row32, int* col32, int* deg) {
    int i = blockIdx.x * 256 + threadIdx.x;
    if (i >= N_EDGES) return;
    int is64 = *flag;
    int r = eidx(edges, is64, i);
    int c = eidx(edges, is64, N_EDGES + i);
    row32[i] = r;
    col32[i] = c;
    atomicAdd(&deg[c], 1);
}

// ---- two-level scan: local scan -> scan of block sums -> apply ----
__global__ __launch_bounds__(SCAN_BS) void k_scan_part(const int* __restrict__ deg,
                                                       int* __restrict__ ptr,
                                                       int* __restrict__ bsum) {
    __shared__ int lds[SCAN_BS];
    int t = threadIdx.x;
    int idx = blockIdx.x * SCAN_BS + t;
    int s = (idx < N_NODES) ? deg[idx] : 0;
    lds[t] = s;
    __syncthreads();
#pragma unroll
    for (int off = 1; off < SCAN_BS; off <<= 1) {
        int v = (t >= off) ? lds[t - off] : 0;
        __syncthreads();
        lds[t] += v;
        __syncthreads();
    }
    if (idx < N_NODES) ptr[idx] = lds[t] - s;     // exclusive local
    if (t == SCAN_BS - 1) bsum[blockIdx.x] = lds[t];
}

__global__ __launch_bounds__(256) void k_scan_bsum(const int* __restrict__ bsum,
                                                   int* __restrict__ boff,
                                                   int* __restrict__ ptr) {
    __shared__ int lds[256];
    int t = threadIdx.x;
    int s = (t < SCAN_NB) ? bsum[t] : 0;
    lds[t] = s;
    __syncthreads();
#pragma unroll
    for (int off = 1; off < 256; off <<= 1) {
        int v = (t >= off) ? lds[t - off] : 0;
        __syncthreads();
        lds[t] += v;
        __syncthreads();
    }
    if (t < SCAN_NB) boff[t] = lds[t] - s;        // exclusive
    if (t == 255) ptr[N_NODES] = lds[t];          // total (== N_EDGES)
}

__global__ __launch_bounds__(SCAN_BS) void k_scan_apply(const int* __restrict__ deg,
                                                        const int* __restrict__ boff,
                                                        int* __restrict__ ptr,
                                                        int* __restrict__ cursor,
                                                        float* __restrict__ dinv) {
    int idx = blockIdx.x * SCAN_BS + threadIdx.x;
    if (idx >= N_NODES) return;
    int p = ptr[idx] + boff[blockIdx.x];
    ptr[idx] = p;
    cursor[idx] = p;
    dinv[idx] = rsqrtf((float)(deg[idx] + 1));    // +1 self loop
}

// XCD-ownership fill: grp = blockIdx%8 owns target range [grp*12500, +12500).
#define FILL_SLICES 128
__global__ __launch_bounds__(256) void k_fill2(const int* __restrict__ row32,
                                               const int* __restrict__ col32,
                                               int* cursor, int* __restrict__ csr_src) {
    int b = blockIdx.x;
    int grp = b & 7;
    int slice = b >> 3;
    int lo = grp * 12500, hi = lo + 12500;
    const int per = (N_EDGES + FILL_SLICES - 1) / FILL_SLICES;  // 25000
    int e0 = slice * per;
    int e1 = min(N_EDGES, e0 + per);
    for (int e = e0 + (int)threadIdx.x; e < e1; e += 256) {
        int c = col32[e];
        if (c >= lo && c < hi) {
            int r = row32[e];
            int p = atomicAdd(&cursor[c], 1);
            csr_src[p] = r;
        }
    }
}

// W1 [500,256] f32 -> W1s bf16 swizzled [ks=16][n=256][kk=32], K zero-padded to 512
__global__ void k_wconv1(const float* W1, u16* W1s) {
    int idx = blockIdx.x * 256 + threadIdx.x;
    if (idx >= 16 * 256 * 32) return;
    int ks = idx / (256 * 32);
    int rem = idx % (256 * 32);
    int n = rem / 32, kk = rem % 32;
    int k = ks * 32 + kk;
    float v = (k < 500) ? W1[k * 256 + n] : 0.0f;
    W1s[idx] = f2bf(v);
}

// W2 [256,64] f32 -> W2s bf16 swizzled [ks=8][n=64][kk=32]
__global__ void k_wconv2(const float* W2, u16* W2s) {
    int idx = blockIdx.x * 256 + threadIdx.x;
    if (idx >= 8 * 64 * 32) return;
    int ks = idx / (64 * 32);
    int rem = idx % (64 * 32);
    int n = rem / 32, kk = rem % 32;
    int k = ks * 32 + kk;
    W2s[idx] = f2bf(W2[k * 64 + n]);
}

// Fused MLP v3: barrier-free MFMA K-loop with DEPTH-3 x prefetch ring.
// The K-loop is fully unrolled so ring indices (ks%3) are compile-time
// constants -> xs stays in registers (no scratch). 12KB/wave of x stays in
// flight (~3 iterations of overlap) to cover loaded HBM latency.
// ks=15 is folded into the ring: addresses clamped (no OOB), and W1s rows
// for k>=500 are zero so clamped garbage contributes nothing.
#define MLP_ROWS 128
#define HSTR 264    // u16 stride for H rows
#define H2STR 72    // u16 stride for pack buffer (16B-aligned rows)

__global__ __launch_bounds__(256, 2) void k_mlp(
    const float* __restrict__ x, const u16* __restrict__ W1s,
    const float* __restrict__ b1, const u16* __restrict__ W2s,
    const float* __restrict__ b2, const float* __restrict__ dinv,
    u16* __restrict__ h_bf, u16* __restrict__ zs0) {

    __shared__ u16 H_lds[MLP_ROWS * HSTR];   // 67584 B

    int t = threadIdx.x;
    int lane = t & 63, w = t >> 6;
    int m0 = blockIdx.x * MLP_ROWS;
    int cl = lane & 15, hi = lane >> 4;

    int row0 = m0 + w * 32 + cl;
    int row1 = row0 + 16;
    int row0c = min(row0, N_NODES - 1);
    int row1c = min(row1, N_NODES - 1);
    const float* xr0 = x + (size_t)row0c * 500 + 8 * hi;
    const float* xr1 = x + (size_t)row1c * 500 + 8 * hi;
    const size_t XMAX = (size_t)N_NODES * 500 - 4;  // last valid float4 start

    f32x4 acc0[16], acc1[16];
    f32x4 zero = {0.f, 0.f, 0.f, 0.f};
#pragma unroll
    for (int i = 0; i < 16; ++i) { acc0[i] = zero; acc1[i] = zero; }

    const u16* bbase = W1s + cl * 32 + 8 * hi;

    // depth-3 prefetch ring (ks = 0,1,2 all have k+31 <= 95 < 500: plain loads)
    float4 xs[3][4];
#pragma unroll
    for (int d = 0; d < 3; ++d) {
        xs[d][0] = *(const float4*)(xr0 + d * 32);
        xs[d][1] = *(const float4*)(xr0 + d * 32 + 4);
        xs[d][2] = *(const float4*)(xr1 + d * 32);
        xs[d][3] = *(const float4*)(xr1 + d * 32 + 4);
    }

#pragma unroll
    for (int ks = 0; ks < 16; ++ks) {
        const int cur = ks % 3;
        bf16x8 af0 = cvt8(xs[cur][0], xs[cur][1]);
        bf16x8 af1 = cvt8(xs[cur][2], xs[cur][3]);
        if (ks + 3 <= 15) {
            const int kn = ks + 3;
            if (kn == 15) {
                // tail: clamp flat index (W1s zero rows null the k>=500 lanes)
                size_t f0 = (size_t)row0c * 500 + 480 + 8 * hi;
                size_t f1 = (size_t)row1c * 500 + 480 + 8 * hi;
                size_t a0 = f0 > XMAX ? XMAX : f0;
                size_t a1 = (f0 + 4) > XMAX ? XMAX : (f0 + 4);
                size_t a2 = f1 > XMAX ? XMAX : f1;
                size_t a3 = (f1 + 4) > XMAX ? XMAX : (f1 + 4);
                xs[cur][0] = *(const float4*)(x + a0);
                xs[cur][1] = *(const float4*)(x + a1);
                xs[cur][2] = *(const float4*)(x + a2);
                xs[cur][3] = *(const float4*)(x + a3);
            } else {
                xs[cur][0] = *(const float4*)(xr0 + kn * 32);
                xs[cur][1] = *(const float4*)(xr0 + kn * 32 + 4);
                xs[cur][2] = *(const float4*)(xr1 + kn * 32);
                xs[cur][3] = *(const float4*)(xr1 + kn * 32 + 4);
            }
        }
        const u16* bp = bbase + ks * 8192;
#pragma unroll
        for (int nt = 0; nt < 16; ++nt) {
            bf16x8 b = *reinterpret_cast<const bf16x8*>(bp + nt * 512);
            acc0[nt] = __builtin_amdgcn_mfma_f32_16x16x32_bf16(af0, b, acc0[nt], 0, 0, 0);
            acc1[nt] = __builtin_amdgcn_mfma_f32_16x16x32_bf16(af1, b, acc1[nt], 0, 0, 0);
        }
    }

    // epilogue 1: +b1, relu -> H_lds (each wave writes ONLY its own 32 rows,
    // and GEMM2 reads only those rows -> no barrier needed before GEMM2)
    {
        int rl0 = w * 32 + hi * 4;
#pragma unroll
        for (int nt = 0; nt < 16; ++nt) {
            int col = nt * 16 + cl;
            float bb = b1[col];
#pragma unroll
            for (int r = 0; r < 4; ++r) {
                float v0 = fmaxf(acc0[nt][r] + bb, 0.0f);
                float v1 = fmaxf(acc1[nt][r] + bb, 0.0f);
                H_lds[(rl0 + r) * HSTR + col] = f2bf(v0);
                H_lds[(rl0 + 16 + r) * HSTR + col] = f2bf(v1);
            }
        }
    }

    // GEMM2: H[32 rows x 256] @ W2s[256 x 64], B direct from global (L2)
    f32x4 acc20[4], acc21[4];
#pragma unroll
    for (int i = 0; i < 4; ++i) { acc20[i] = zero; acc21[i] = zero; }
    int rA0 = w * 32 + cl;
#pragma unroll
    for (int ks2 = 0; ks2 < 8; ++ks2) {
        bf16x8 af0 = *reinterpret_cast<const bf16x8*>(&H_lds[rA0 * HSTR + ks2 * 32 + 8 * hi]);
        bf16x8 af1 = *reinterpret_cast<const bf16x8*>(&H_lds[(rA0 + 16) * HSTR + ks2 * 32 + 8 * hi]);
#pragma unroll
        for (int nt = 0; nt < 4; ++nt) {
            bf16x8 b = *reinterpret_cast<const bf16x8*>(W2s + (ks2 * 64 + nt * 16 + cl) * 32 + 8 * hi);
            acc20[nt] = __builtin_amdgcn_mfma_f32_16x16x32_bf16(af0, b, acc20[nt], 0, 0, 0);
            acc21[nt] = __builtin_amdgcn_mfma_f32_16x16x32_bf16(af1, b, acc21[nt], 0, 0, 0);
        }
    }
    __syncthreads();   // all waves done reading H_lds; safe to overwrite as H2

    // epilogue 2: +b2 -> pack buffer H2 (reuses H_lds memory)
    u16* H2 = H_lds;
    {
        int rl0 = w * 32 + hi * 4;
#pragma unroll
        for (int nt = 0; nt < 4; ++nt) {
            int col = nt * 16 + cl;
            float bb = b2[col];
#pragma unroll
            for (int r = 0; r < 4; ++r) {
                H2[(rl0 + r) * H2STR + col] = f2bf(acc20[nt][r] + bb);
                H2[(rl0 + 16 + r) * H2STR + col] = f2bf(acc21[nt][r] + bb);
            }
        }
    }
    __syncthreads();

    // pack & store: thread t handles half a row (32 u16 = 64B), coalesced
    {
        int rl = t >> 1, half = t & 1;
        int grow = m0 + rl;
        if (grow < N_NODES) {
            float dv = dinv[grow];
            const uint4* src = (const uint4*)&H2[rl * H2STR + half * 32];
            uint4 q0 = src[0], q1 = src[1], q2 = src[2], q3 = src[3];
            uint4 hq[4] = {q0, q1, q2, q3};
            uint4 zq[4];
#pragma unroll
            for (int i = 0; i < 4; ++i) {
                unsigned int* hw = (unsigned int*)&hq[i];
                unsigned int* zw = (unsigned int*)&zq[i];
#pragma unroll
                for (int jj = 0; jj < 4; ++jj) {
                    float lo = dv * bf2f_lo(hw[jj]);
                    float hi2 = dv * bf2f_hi(hw[jj]);
                    zw[jj] = (unsigned)f2bf(lo) | ((unsigned)f2bf(hi2) << 16);
                }
            }
            uint4* hd = (uint4*)(h_bf + (size_t)grow * 64 + half * 32);
            uint4* zd = (uint4*)(zs0 + (size_t)grow * 64 + half * 32);
            hd[0] = hq[0]; hd[1] = hq[1]; hd[2] = hq[2]; hd[3] = hq[3];
            zd[0] = zq[0]; zd[1] = zq[1]; zd[2] = zq[2]; zd[3] = zq[3];
        }
    }
}

// Propagation v3 (unchanged): one wave per node, dwordx4 gathers of 8 edges.
__global__ __launch_bounds__(256) void k_prop3(
    const u16* __restrict__ zs_in, const u16* __restrict__ h_bf,
    const float* __restrict__ dinv, const int* __restrict__ ptr,
    const int* __restrict__ csr_src, u16* __restrict__ zs_out,
    float* __restrict__ out, int last) {

    int lane = threadIdx.x & 63;
    int g = lane >> 3;   // edge slot 0..7
    int c = lane & 7;    // channels 8c..8c+7
    int v = blockIdx.x * 4 + (threadIdx.x >> 6);
    if (v >= N_NODES) return;
    int s0 = ptr[v], s1 = ptr[v + 1];

    float a0 = 0.f, a1 = 0.f, a2 = 0.f, a3 = 0.f;
    float a4 = 0.f, a5 = 0.f, a6 = 0.f, a7 = 0.f;
    float b0 = 0.f, b1 = 0.f, b2 = 0.f, b3 = 0.f;
    float b4 = 0.f, b5 = 0.f, b6 = 0.f, b7 = 0.f;

    for (int base = s0; base < s1; base += 64) {
        int nwin = min(64, s1 - base);
        int ei = base + lane;
        int sv = (ei < s1) ? csr_src[ei] : v;   // fallback: safe address
        int j = 0;
        for (; j + 16 <= nwin; j += 16) {
            int u0 = __shfl(sv, j + g, 64);
            int u1 = __shfl(sv, j + 8 + g, 64);
            uint4 q0 = *(const uint4*)(zs_in + (size_t)u0 * 64 + c * 8);
            uint4 q1 = *(const uint4*)(zs_in + (size_t)u1 * 64 + c * 8);
            a0 += bf2f_lo(q0.x); a1 += bf2f_hi(q0.x);
            a2 += bf2f_lo(q0.y); a3 += bf2f_hi(q0.y);
            a4 += bf2f_lo(q0.z); a5 += bf2f_hi(q0.z);
            a6 += bf2f_lo(q0.w); a7 += bf2f_hi(q0.w);
            b0 += bf2f_lo(q1.x); b1 += bf2f_hi(q1.x);
            b2 += bf2f_lo(q1.y); b3 += bf2f_hi(q1.y);
            b4 += bf2f_lo(q1.z); b5 += bf2f_hi(q1.z);
            b6 += bf2f_lo(q1.w); b7 += bf2f_hi(q1.w);
        }
        for (; j < nwin; j += 8) {
            int idx = j + g;
            int u = __shfl(sv, idx, 64);  // idx<=63; invalid lanes hold v (safe)
            uint4 q = *(const uint4*)(zs_in + (size_t)u * 64 + c * 8);
            if (idx < nwin) {
                a0 += bf2f_lo(q.x); a1 += bf2f_hi(q.x);
                a2 += bf2f_lo(q.y); a3 += bf2f_hi(q.y);
                a4 += bf2f_lo(q.z); a5 += bf2f_hi(q.z);
                a6 += bf2f_lo(q.w); a7 += bf2f_hi(q.w);
            }
        }
    }
    a0 += b0; a1 += b1; a2 += b2; a3 += b3;
    a4 += b4; a5 += b5; a6 += b6; a7 += b7;
#pragma unroll
    for (int off = 8; off <= 32; off <<= 1) {
        a0 += __shfl_xor(a0, off, 64); a1 += __shfl_xor(a1, off, 64);
        a2 += __shfl_xor(a2, off, 64); a3 += __shfl_xor(a3, off, 64);
        a4 += __shfl_xor(a4, off, 64); a5 += __shfl_xor(a5, off, 64);
        a6 += __shfl_xor(a6, off, 64); a7 += __shfl_xor(a7, off, 64);
    }

    float dv = dinv[v];
    uint4 qs = *(const uint4*)(zs_in + (size_t)v * 64 + c * 8);
    uint4 qh = *(const uint4*)(h_bf + (size_t)v * 64 + c * 8);
    float z0 = (1.0f - ALPHA) * dv * (a0 + bf2f_lo(qs.x)) + ALPHA * bf2f_lo(qh.x);
    float z1 = (1.0f - ALPHA) * dv * (a1 + bf2f_hi(qs.x)) + ALPHA * bf2f_hi(qh.x);
    float z2 = (1.0f - ALPHA) * dv * (a2 + bf2f_lo(qs.y)) + ALPHA * bf2f_lo(qh.y);
    float z3 = (1.0f - ALPHA) * dv * (a3 + bf2f_hi(qs.y)) + ALPHA * bf2f_hi(qh.y);
    float z4 = (1.0f - ALPHA) * dv * (a4 + bf2f_lo(qs.z)) + ALPHA * bf2f_lo(qh.z);
    float z5 = (1.0f - ALPHA) * dv * (a5 + bf2f_hi(qs.z)) + ALPHA * bf2f_hi(qh.z);
    float z6 = (1.0f - ALPHA) * dv * (a6 + bf2f_lo(qs.w)) + ALPHA * bf2f_lo(qh.w);
    float z7 = (1.0f - ALPHA) * dv * (a7 + bf2f_hi(qs.w)) + ALPHA * bf2f_hi(qh.w);

    if (!last) {
        if (g == 0) {
            uint4 o;
            o.x = (unsigned)f2bf(dv * z0) | ((unsigned)f2bf(dv * z1) << 16);
            o.y = (unsigned)f2bf(dv * z2) | ((unsigned)f2bf(dv * z3) << 16);
            o.z = (unsigned)f2bf(dv * z4) | ((unsigned)f2bf(dv * z5) << 16);
            o.w = (unsigned)f2bf(dv * z6) | ((unsigned)f2bf(dv * z7) << 16);
            *(uint4*)(zs_out + (size_t)v * 64 + c * 8) = o;
        }
    } else {
        float m = fmaxf(fmaxf(fmaxf(z0, z1), fmaxf(z2, z3)),
                        fmaxf(fmaxf(z4, z5), fmaxf(z6, z7)));
#pragma unroll
        for (int off = 1; off <= 4; off <<= 1) m = fmaxf(m, __shfl_xor(m, off, 64));
        float p = expf(z0 - m) + expf(z1 - m) + expf(z2 - m) + expf(z3 - m)
                + expf(z4 - m) + expf(z5 - m) + expf(z6 - m) + expf(z7 - m);
#pragma unroll
        for (int off = 1; off <= 4; off <<= 1) p += __shfl_xor(p, off, 64);
        float ls = logf(p);
        if (g == 0) {
            float4 o1 = {z0 - m - ls, z1 - m - ls, z2 - m - ls, z3 - m - ls};
            float4 o2 = {z4 - m - ls, z5 - m - ls, z6 - m - ls, z7 - m - ls};
            *(float4*)(out + (size_t)v * 64 + c * 8) = o1;
            *(float4*)(out + (size_t)v * 64 + c * 8 + 4) = o2;
        }
    }
}

extern "C" void kernel_launch(void* const* d_in, const int* in_sizes, int n_in,
                              void* d_out, int out_size, void* d_ws, size_t ws_size,
                              hipStream_t stream) {
    const float* x  = (const float*)d_in[0];
    const void* edges = d_in[1];
    const float* W1 = (const float*)d_in[2];
    const float* b1 = (const float*)d_in[3];
    const float* W2 = (const float*)d_in[4];
    const float* b2 = (const float*)d_in[5];
    float* out = (float*)d_out;

    char* ws = (char*)d_ws;
    size_t off = 0;
    auto alloc = [&](size_t bytes) -> void* {
        void* p = ws + off;
        off = (off + bytes + 255) & ~(size_t)255;
        return p;
    };
    int*   flag    = (int*)alloc(4);
    int*   deg     = (int*)alloc((size_t)N_NODES * 4);
    float* dinv    = (float*)alloc((size_t)N_NODES * 4);
    int*   ptr     = (int*)alloc((size_t)(N_NODES + 1) * 4);
    int*   cursor  = (int*)alloc((size_t)N_NODES * 4);
    int*   bsum    = (int*)alloc((size_t)SCAN_NB * 4);
    int*   boff    = (int*)alloc((size_t)SCAN_NB * 4);
    int*   csr_src = (int*)alloc((size_t)N_EDGES * 4);
    u16*   W1s     = (u16*)alloc((size_t)16 * 256 * 32 * 2);
    u16*   W2s     = (u16*)alloc((size_t)8 * 64 * 32 * 2);
    u16*   h_bf    = (u16*)alloc((size_t)N_NODES * 64 * 2);
    u16*   zsA     = (u16*)alloc((size_t)N_NODES * 64 * 2);
    int*   row32   = (int*)alloc((size_t)N_EDGES * 4);  // aliased as zsB after fill
    int*   col32   = (int*)alloc((size_t)N_EDGES * 4);
    u16*   zsB     = (u16*)row32;  // row32 dead after k_fill2; N_EDGES*4 == N*64*2

    hipMemsetAsync(deg, 0, (size_t)N_NODES * 4, stream);
    k_detect<<<1, 64, 0, stream>>>((const unsigned int*)edges, flag);
    k_convert_count<<<(N_EDGES + 255) / 256, 256, 0, stream>>>(edges, flag, row32, col32, deg);
    k_scan_part<<<SCAN_NB, SCAN_BS, 0, stream>>>(deg, ptr, bsum);
    k_scan_bsum<<<1, 256, 0, stream>>>(bsum, boff, ptr);
    k_scan_apply<<<SCAN_NB, SCAN_BS, 0, stream>>>(deg, boff, ptr, cursor, dinv);
    k_fill2<<<8 * FILL_SLICES, 256, 0, stream>>>(row32, col32, cursor, csr_src);
    k_wconv1<<<(16 * 256 * 32 + 255) / 256, 256, 0, stream>>>(W1, W1s);
    k_wconv2<<<(8 * 64 * 32 + 255) / 256, 256, 0, stream>>>(W2, W2s);
    k_mlp<<<(N_NODES + MLP_ROWS - 1) / MLP_ROWS, 256, 0, stream>>>(x, W1s, b1, W2s, b2,
                                                                   dinv, h_bf, zsA);

    const u16* zin = zsA;
    u16* zout = zsB;
    for (int k = 0; k < KITER; ++k) {
        int last = (k == KITER - 1) ? 1 : 0;
        k_prop3<<<(N_NODES + 3) / 4, 256, 0, stream>>>(zin, h_bf, dinv, ptr, csr_src,
                                                       zout, out, last);
        u16* t = zout;
        zout = (u16*)zin;
        zin = t;
    }
}